// Round 7
// baseline (4379.440 us; speedup 1.0000x reference)
//
#include <hip/hip_runtime.h>
#include <cmath>

// B=2, S=4096, DM=768, H=12, FF=3072, BLOCK=64, NB=64, R=3, d=64
// Inputs f32. Peak d_ws usage: 2 * 8192*768 * 2B = 25.2 MB.
//   ws0: K bf16  -> later h1 bf16
//   ws1: V bf16  -> later f1c bf16
//   d_out: Q f32 -> ctx f32 (in-place attn) -> f2 f32 -> final out f32
// ROUND 7 FIX: gemm As tile was [16][68] but m-dim is 128 -> LDS OOB + warp race.

typedef unsigned short bf;

__device__ __forceinline__ float bf2f(bf u) { return __uint_as_float(((unsigned)u) << 16); }
__device__ __forceinline__ bf f2bf(float f) {
  unsigned x = __float_as_uint(f);
  x += 0x7FFFu + ((x >> 16) & 1u);   // round-to-nearest-even
  return (bf)(x >> 16);
}

__device__ __forceinline__ float4 ld4f(const float* p) { return *(const float4*)p; }
__device__ __forceinline__ float4 ld4f(const bf* p) {
  ushort4 u = *(const ushort4*)p;
  return make_float4(bf2f(u.x), bf2f(u.y), bf2f(u.z), bf2f(u.w));
}

// ---- GEMM: C = [beta*C] + A(MxK)*B(K x N, row-stride ldb) [+ bias] [GELU] ----
// tile 128x64, BK=16, 256 threads, 8x4 micro-tile. C row stride = N.
template <typename TA, typename TC>
__global__ __launch_bounds__(256) void gemm_k(
    const TA* __restrict__ A, const float* __restrict__ B,
    const float* __restrict__ bias, TC* __restrict__ C,
    int M, int N, int K, int ldb, int ep, int beta)
{
  __shared__ float As[16][132];  // [k][m], m-tile=128 + 4 pad  (ROUND 7 FIX)
  __shared__ float Bs[16][68];   // [k][n], n-tile=64 + 4 pad
  const int t = threadIdx.x;
  const int bm = blockIdx.y * 128, bn = blockIdx.x * 64;
  float acc[8][4];
  #pragma unroll
  for (int i = 0; i < 8; ++i)
    #pragma unroll
    for (int j = 0; j < 4; ++j) acc[i][j] = 0.f;
  const int tm4 = (t & 15) * 4;
  const int tn  = (t >> 4) * 4;
  for (int k0 = 0; k0 < K; k0 += 16) {
    #pragma unroll
    for (int c = 0; c < 2; ++c) {
      int f = t + 256 * c;
      int row = f >> 2, kk = (f & 3) * 4;
      float4 a4 = ld4f(&A[(size_t)(bm + row) * K + (k0 + kk)]);
      As[kk + 0][row] = a4.x; As[kk + 1][row] = a4.y;
      As[kk + 2][row] = a4.z; As[kk + 3][row] = a4.w;
    }
    {
      int kk = t >> 4, nn = (t & 15) * 4;
      *(float4*)&Bs[kk][nn] = ld4f(&B[(size_t)(k0 + kk) * ldb + (bn + nn)]);
    }
    __syncthreads();
    #pragma unroll
    for (int k = 0; k < 16; ++k) {
      float4 a0 = *(const float4*)&As[k][tm4];
      float4 a1 = *(const float4*)&As[k][64 + tm4];
      float4 b0 = *(const float4*)&Bs[k][tn];
      float av[8] = {a0.x, a0.y, a0.z, a0.w, a1.x, a1.y, a1.z, a1.w};
      float bw[4] = {b0.x, b0.y, b0.z, b0.w};
      #pragma unroll
      for (int i = 0; i < 8; ++i)
        #pragma unroll
        for (int j = 0; j < 4; ++j) acc[i][j] = fmaf(av[i], bw[j], acc[i][j]);
    }
    __syncthreads();
  }
  #pragma unroll
  for (int i = 0; i < 8; ++i) {
    int row = bm + ((i < 4) ? (tm4 + i) : (64 + tm4 + i - 4));
    #pragma unroll
    for (int j = 0; j < 4; ++j) {
      size_t idx = (size_t)row * N + bn + tn + j;
      float v = acc[i][j];
      if (bias) v += bias[bn + tn + j];
      if (ep == 1) v = 0.5f * v * (1.0f + erff(v * 0.70710678118654752f));
      if (beta) {
        if constexpr (sizeof(TC) == 2) v += bf2f(C[idx]);
        else                           v += C[idx];
      }
      if constexpr (sizeof(TC) == 2) C[idx] = f2bf(v);
      else                           C[idx] = v;
    }
  }
}

// ---------------- BigBird attention, one WG per (b,h,qblock) ----------------
// Q f32 (d_out); K,V bf16 (ws); ctx written in-place over Q's region.
__global__ __launch_bounds__(256) void attn_kernel(
    const float* __restrict__ Q, const bf* __restrict__ K,
    const bf* __restrict__ V, const int* __restrict__ rnd,
    float* __restrict__ ctx)
{
  __shared__ float qs[64][68];    // [qrow][d]
  __shared__ float kvT[64][65];   // [d][key]
  __shared__ float sb[64][67];    // [qrow][key]
  __shared__ float mrow[64], lrow[64], crow[64];
  __shared__ int klist[64];
  __shared__ int nkb_s;
  const int t = threadIdx.x;
  const int wg = blockIdx.x;
  const int n = wg & 63;
  const int h = (wg >> 6) % 12;
  const int b = wg / 768;
  if (t == 0) {
    int cnt = 0;
    if (n == 0 || n == 63) {
      for (int i = 0; i < 64; ++i) klist[cnt++] = i;
    } else if (n == 1) {
      klist[cnt++] = 0; klist[cnt++] = 1; klist[cnt++] = 2; klist[cnt++] = 63;
      for (int j = 0; j < 3; ++j) klist[cnt++] = rnd[(h * 62 + 0) * 3 + j];
    } else if (n == 62) {
      klist[cnt++] = 0; klist[cnt++] = 61; klist[cnt++] = 62; klist[cnt++] = 63;
      for (int j = 0; j < 3; ++j) klist[cnt++] = rnd[(h * 62 + 61) * 3 + j];
    } else {
      klist[cnt++] = 0; klist[cnt++] = n - 1; klist[cnt++] = n; klist[cnt++] = n + 1;
      for (int j = 0; j < 3; ++j) klist[cnt++] = rnd[(h * 62 + (n - 1)) * 3 + j];
      klist[cnt++] = 63;
    }
    nkb_s = cnt;
  }
  const size_t qbase = (((size_t)b * 4096) + (size_t)n * 64) * 768 + h * 64;
  #pragma unroll
  for (int c = 0; c < 4; ++c) {
    int f = t + 256 * c;
    int row = f >> 4, c4 = (f & 15) * 4;
    *(float4*)&qs[row][c4] = *(const float4*)&Q[qbase + (size_t)row * 768 + c4];
  }
  if (t < 64) { mrow[t] = -1e30f; lrow[t] = 0.f; }
  float o[16];
  #pragma unroll
  for (int i = 0; i < 16; ++i) o[i] = 0.f;
  const int r   = t & 63;
  const int grp = t >> 6;
  const int i0  = grp * 16;
  const int dd0 = grp * 16;
  __syncthreads();
  const int nkb = nkb_s;
  for (int ib = 0; ib < nkb; ++ib) {
    const int kb = klist[ib];
    const size_t kbase = (((size_t)b * 4096) + (size_t)kb * 64) * 768 + h * 64;
    #pragma unroll
    for (int c = 0; c < 4; ++c) {
      int f = t + 256 * c;
      int row = f >> 4, c4 = (f & 15) * 4;
      float4 kv = ld4f(&K[kbase + (size_t)row * 768 + c4]);
      kvT[c4 + 0][row] = kv.x; kvT[c4 + 1][row] = kv.y;
      kvT[c4 + 2][row] = kv.z; kvT[c4 + 3][row] = kv.w;
    }
    __syncthreads();
    {
      float accs[16];
      #pragma unroll
      for (int i = 0; i < 16; ++i) accs[i] = 0.f;
      for (int dd = 0; dd < 64; ++dd) {
        float kvv = kvT[dd][r];
        #pragma unroll
        for (int ii = 0; ii < 16; ++ii)
          accs[ii] = fmaf(qs[i0 + ii][dd], kvv, accs[ii]);
      }
      #pragma unroll
      for (int ii = 0; ii < 16; ++ii) sb[i0 + ii][r] = accs[ii] * 0.125f;
    }
    __syncthreads();
    #pragma unroll
    for (int c = 0; c < 4; ++c) {
      int f = t + 256 * c;
      int row = f >> 4, c4 = (f & 15) * 4;
      float4 vv = ld4f(&V[kbase + (size_t)row * 768 + c4]);
      kvT[c4 + 0][row] = vv.x; kvT[c4 + 1][row] = vv.y;
      kvT[c4 + 2][row] = vv.z; kvT[c4 + 3][row] = vv.w;
    }
    if (t < 64) {
      float m_old = mrow[t];
      float mx = m_old;
      for (int j = 0; j < 64; ++j) mx = fmaxf(mx, sb[t][j]);
      float c_ = expf(m_old - mx);
      float sum = 0.f;
      for (int j = 0; j < 64; ++j) {
        float p = expf(sb[t][j] - mx);
        sb[t][j] = p;
        sum += p;
      }
      crow[t] = c_;
      lrow[t] = lrow[t] * c_ + sum;
      mrow[t] = mx;
    }
    __syncthreads();
    {
      float c_ = crow[r];
      #pragma unroll
      for (int ii = 0; ii < 16; ++ii) o[ii] *= c_;
      for (int j = 0; j < 64; ++j) {
        float p = sb[r][j];
        #pragma unroll
        for (int ii = 0; ii < 16; ++ii)
          o[ii] = fmaf(p, kvT[dd0 + ii][j], o[ii]);
      }
    }
    __syncthreads();
  }
  const float invl = 1.0f / lrow[r];
  #pragma unroll
  for (int ii = 0; ii < 16; ++ii) sb[r][dd0 + ii] = o[ii] * invl;
  __syncthreads();
  #pragma unroll
  for (int c = 0; c < 16; ++c) {
    int f = t + 256 * c;
    int i = f >> 6, dd = f & 63;
    ctx[qbase + (size_t)i * 768 + dd] = sb[i][dd];
  }
}

// ---------------- LayerNorm(a + res) * g + b ----------------
template <typename TR, typename TO>
__global__ __launch_bounds__(256) void ln_kernel(
    const float* __restrict__ a, const TR* __restrict__ res,
    const float* __restrict__ g, const float* __restrict__ bb,
    TO* __restrict__ out)
{
  const int row = blockIdx.x, t = threadIdx.x;
  __shared__ float buf[768];
  __shared__ float rs[4], rss[4];
  const size_t base = (size_t)row * 768;
  float s = 0.f, ss = 0.f;
  for (int c = t; c < 768; c += 256) {
    float rv;
    if constexpr (sizeof(TR) == 2) rv = bf2f(res[base + c]);
    else                           rv = res[base + c];
    float v = a[base + c] + rv;
    buf[c] = v;
    s += v;
    ss = fmaf(v, v, ss);
  }
  #pragma unroll
  for (int off = 32; off > 0; off >>= 1) {
    s  += __shfl_down(s, off, 64);
    ss += __shfl_down(ss, off, 64);
  }
  if ((t & 63) == 0) { rs[t >> 6] = s; rss[t >> 6] = ss; }
  __syncthreads();
  float S  = rs[0] + rs[1] + rs[2] + rs[3];
  float SS = rss[0] + rss[1] + rss[2] + rss[3];
  float mu  = S * (1.f / 768.f);
  float var = SS * (1.f / 768.f) - mu * mu;
  float inv = rsqrtf(var + 1e-5f);
  for (int c = t; c < 768; c += 256) {
    float v = (buf[c] - mu) * inv * g[c] + bb[c];
    if constexpr (sizeof(TO) == 2) out[base + c] = f2bf(v);
    else                           out[base + c] = v;
  }
}

extern "C" void kernel_launch(void* const* d_in, const int* in_sizes, int n_in,
                              void* d_out, int out_size, void* d_ws, size_t ws_size,
                              hipStream_t stream)
{
  const float* x   = (const float*)d_in[0];
  const int*   rnd = (const int*)d_in[1];
  const float* Wq  = (const float*)d_in[2];
  const float* bq  = (const float*)d_in[3];
  const float* Wk  = (const float*)d_in[4];
  const float* bk  = (const float*)d_in[5];
  const float* Wv  = (const float*)d_in[6];
  const float* bv  = (const float*)d_in[7];
  const float* g1  = (const float*)d_in[8];
  const float* be1 = (const float*)d_in[9];
  const float* W1  = (const float*)d_in[10];
  const float* b1  = (const float*)d_in[11];
  const float* W2  = (const float*)d_in[12];
  const float* b2  = (const float*)d_in[13];
  const float* g2  = (const float*)d_in[14];
  const float* be2 = (const float*)d_in[15];
  float* out = (float*)d_out;

  const size_t MT = 8192;  // B*S rows
  bf* Kb  = (bf*)d_ws;           // 8192*768 bf16 (12.6 MB)
  bf* Vb  = Kb + MT * 768;       // 8192*768 bf16 (12.6 MB)
  float* Qb  = out;              // Q f32 in d_out; attn runs in-place
  float* ctx = out;
  bf* h1  = Kb;                  // reuses K slot after attention
  bf* f1c = Vb;                  // reuses V slot after attention
  float* f2 = out;               // FFN accumulator in d_out

  dim3 blk(256);
  dim3 g768(768 / 64, MT / 128);
  gemm_k<float, float><<<g768, blk, 0, stream>>>(x, Wq, bq, Qb, MT, 768, 768, 768, 0, 0);
  gemm_k<float, bf   ><<<g768, blk, 0, stream>>>(x, Wk, bk, Kb, MT, 768, 768, 768, 0, 0);
  gemm_k<float, bf   ><<<g768, blk, 0, stream>>>(x, Wv, bv, Vb, MT, 768, 768, 768, 0, 0);
  attn_kernel<<<dim3(2 * 12 * 64), blk, 0, stream>>>(Qb, Kb, Vb, rnd, ctx);
  ln_kernel<float, bf><<<dim3(MT), blk, 0, stream>>>(ctx, x, g1, be1, h1);
  // FFN in 4 chunks of 768 over the FF dimension; f2 (d_out) accumulates.
  for (int c = 0; c < 4; ++c) {
    gemm_k<bf, bf   ><<<g768, blk, 0, stream>>>(h1, W1 + c * 768, b1 + c * 768, f1c,
                                                MT, 768, 768, 3072, 1, 0);
    gemm_k<bf, float><<<g768, blk, 0, stream>>>(f1c, W2 + (size_t)c * 768 * 768,
                                                (c == 0 ? b2 : (const float*)nullptr), f2,
                                                MT, 768, 768, 768, 0, (c == 0 ? 0 : 1));
  }
  ln_kernel<bf, float><<<dim3(MT), blk, 0, stream>>>(f2, h1, g2, be2, out);
}

// Round 8
// 2034.656 us; speedup vs baseline: 2.1524x; 2.1524x over previous
//
#include <hip/hip_runtime.h>
#include <cmath>

// B=2, S=4096, DM=768, H=12, FF=3072, BLOCK=64, NB=64, R=3, d=64
// Inputs f32. Peak d_ws usage: 2 * 8192*768 * 2B = 25.2 MB.
// Round 8: attention rewrite — q-split for full-attn blocks + register-tiled
// float4 phases. GEMM/LN identical to round 7 (clean A/B).

typedef unsigned short bf;

__device__ __forceinline__ float bf2f(bf u) { return __uint_as_float(((unsigned)u) << 16); }
__device__ __forceinline__ bf f2bf(float f) {
  unsigned x = __float_as_uint(f);
  x += 0x7FFFu + ((x >> 16) & 1u);   // round-to-nearest-even
  return (bf)(x >> 16);
}

__device__ __forceinline__ float4 ld4f(const float* p) { return *(const float4*)p; }
__device__ __forceinline__ float4 ld4f(const bf* p) {
  ushort4 u = *(const ushort4*)p;
  return make_float4(bf2f(u.x), bf2f(u.y), bf2f(u.z), bf2f(u.w));
}
__device__ __forceinline__ void fma4(float4& a, float s, const float4& v) {
  a.x = fmaf(s, v.x, a.x); a.y = fmaf(s, v.y, a.y);
  a.z = fmaf(s, v.z, a.z); a.w = fmaf(s, v.w, a.w);
}

// ---- GEMM: C = [beta*C] + A(MxK)*B(K x N, row-stride ldb) [+ bias] [GELU] ----
// tile 128x64, BK=16, 256 threads, 8x4 micro-tile. C row stride = N.
template <typename TA, typename TC>
__global__ __launch_bounds__(256) void gemm_k(
    const TA* __restrict__ A, const float* __restrict__ B,
    const float* __restrict__ bias, TC* __restrict__ C,
    int M, int N, int K, int ldb, int ep, int beta)
{
  __shared__ float As[16][132];  // [k][m], m-tile=128 + 4 pad
  __shared__ float Bs[16][68];   // [k][n], n-tile=64 + 4 pad
  const int t = threadIdx.x;
  const int bm = blockIdx.y * 128, bn = blockIdx.x * 64;
  float acc[8][4];
  #pragma unroll
  for (int i = 0; i < 8; ++i)
    #pragma unroll
    for (int j = 0; j < 4; ++j) acc[i][j] = 0.f;
  const int tm4 = (t & 15) * 4;
  const int tn  = (t >> 4) * 4;
  for (int k0 = 0; k0 < K; k0 += 16) {
    #pragma unroll
    for (int c = 0; c < 2; ++c) {
      int f = t + 256 * c;
      int row = f >> 2, kk = (f & 3) * 4;
      float4 a4 = ld4f(&A[(size_t)(bm + row) * K + (k0 + kk)]);
      As[kk + 0][row] = a4.x; As[kk + 1][row] = a4.y;
      As[kk + 2][row] = a4.z; As[kk + 3][row] = a4.w;
    }
    {
      int kk = t >> 4, nn = (t & 15) * 4;
      *(float4*)&Bs[kk][nn] = ld4f(&B[(size_t)(k0 + kk) * ldb + (bn + nn)]);
    }
    __syncthreads();
    #pragma unroll
    for (int k = 0; k < 16; ++k) {
      float4 a0 = *(const float4*)&As[k][tm4];
      float4 a1 = *(const float4*)&As[k][64 + tm4];
      float4 b0 = *(const float4*)&Bs[k][tn];
      float av[8] = {a0.x, a0.y, a0.z, a0.w, a1.x, a1.y, a1.z, a1.w};
      float bw[4] = {b0.x, b0.y, b0.z, b0.w};
      #pragma unroll
      for (int i = 0; i < 8; ++i)
        #pragma unroll
        for (int j = 0; j < 4; ++j) acc[i][j] = fmaf(av[i], bw[j], acc[i][j]);
    }
    __syncthreads();
  }
  #pragma unroll
  for (int i = 0; i < 8; ++i) {
    int row = bm + ((i < 4) ? (tm4 + i) : (64 + tm4 + i - 4));
    #pragma unroll
    for (int j = 0; j < 4; ++j) {
      size_t idx = (size_t)row * N + bn + tn + j;
      float v = acc[i][j];
      if (bias) v += bias[bn + tn + j];
      if (ep == 1) v = 0.5f * v * (1.0f + erff(v * 0.70710678118654752f));
      if (beta) {
        if constexpr (sizeof(TC) == 2) v += bf2f(C[idx]);
        else                           v += C[idx];
      }
      if constexpr (sizeof(TC) == 2) C[idx] = f2bf(v);
      else                           C[idx] = v;
    }
  }
}

// ---------------- BigBird attention v2 ----------------
// WGs 0..191: heavy (n=0 or 63, full attention), 16 q-rows per WG (4 chunks).
// WGs 192..1679: light (n=1..62), 64 q-rows, 7-8 key blocks.
__global__ __launch_bounds__(256) void attn2_kernel(
    const float* __restrict__ Q, const bf* __restrict__ K,
    const bf* __restrict__ V, const int* __restrict__ rnd,
    float* __restrict__ ctx)
{
  __shared__ float qs[64][68];
  __shared__ float kv[64][68];   // K^T ([d][key]) then V ([key][d]) each iter
  __shared__ float sb[64][68];   // scores/probs [qrow][key]
  __shared__ float mrow[64], lrow[64], crow[64];
  __shared__ int klist[8];
  const int t = threadIdx.x;
  const int wg = blockIdx.x;
  const bool heavy = wg < 192;
  int b, h, n, r0 = 0, nkb;
  if (heavy) {
    int chunk = wg & 3;
    n = ((wg >> 2) & 1) ? 63 : 0;
    int bh = wg >> 3;  h = bh % 12;  b = bh / 12;
    r0 = chunk * 16;  nkb = 64;
  } else {
    int idx = wg - 192;
    n = 1 + idx % 62;
    int bh = idx / 62;  h = bh % 12;  b = bh / 12;
    nkb = (n == 1 || n == 62) ? 7 : 8;
    if (t == 0) {
      int cnt = 0;
      if (n == 1)       { klist[cnt++] = 0; klist[cnt++] = 1;  klist[cnt++] = 2;  klist[cnt++] = 63; }
      else if (n == 62) { klist[cnt++] = 0; klist[cnt++] = 61; klist[cnt++] = 62; klist[cnt++] = 63; }
      else              { klist[cnt++] = 0; klist[cnt++] = n - 1; klist[cnt++] = n; klist[cnt++] = n + 1; }
      for (int j = 0; j < 3; ++j) klist[cnt++] = rnd[(h * 62 + (n - 1)) * 3 + j];
      if (n != 1 && n != 62) klist[cnt++] = 63;
    }
  }
  const size_t qbase = ((size_t)b * 4096 + (size_t)n * 64) * 768 + h * 64;
  const int tr = t >> 4, tc = t & 15, c4 = tc * 4;

  // stage Q
  if (heavy) {
    *(float4*)&qs[tr][c4] = ld4f(&Q[qbase + (size_t)(r0 + tr) * 768 + c4]);
  } else {
    #pragma unroll
    for (int c = 0; c < 4; ++c) {
      int f = t + 256 * c; int row = f >> 4, cc = (f & 15) * 4;
      *(float4*)&qs[row][cc] = ld4f(&Q[qbase + (size_t)row * 768 + cc]);
    }
  }
  if (t < 64) { mrow[t] = -1e30f; lrow[t] = 0.f; }
  float4 o0 = {0,0,0,0}, o1 = {0,0,0,0}, o2 = {0,0,0,0}, o3 = {0,0,0,0};
  __syncthreads();

  for (int ib = 0; ib < nkb; ++ib) {
    const int kb = heavy ? ib : klist[ib];
    const size_t kbase = ((size_t)b * 4096 + (size_t)kb * 64) * 768 + h * 64;
    // stage K^T: thread covers key j=t&63, d-range (t>>6)*16..+16 (LDS conflict-free)
    {
      int j = t & 63, db = (t >> 6) * 16;
      const bf* kp = &K[kbase + (size_t)j * 768 + db];
      #pragma unroll
      for (int u = 0; u < 4; ++u) {
        ushort4 uv = *(const ushort4*)(kp + u * 4);
        kv[db + u*4 + 0][j] = bf2f(uv.x); kv[db + u*4 + 1][j] = bf2f(uv.y);
        kv[db + u*4 + 2][j] = bf2f(uv.z); kv[db + u*4 + 3][j] = bf2f(uv.w);
      }
    }
    __syncthreads();
    // phase A: S = Q K^T * 0.125
    if (heavy) {
      float4 acc = {0,0,0,0};
      #pragma unroll
      for (int dd = 0; dd < 64; dd += 4) {
        float4 q  = *(float4*)&qs[tr][dd];
        float4 k0 = *(float4*)&kv[dd+0][c4], k1 = *(float4*)&kv[dd+1][c4];
        float4 k2 = *(float4*)&kv[dd+2][c4], k3 = *(float4*)&kv[dd+3][c4];
        fma4(acc, q.x, k0); fma4(acc, q.y, k1); fma4(acc, q.z, k2); fma4(acc, q.w, k3);
      }
      acc.x *= 0.125f; acc.y *= 0.125f; acc.z *= 0.125f; acc.w *= 0.125f;
      *(float4*)&sb[tr][c4] = acc;
    } else {
      float4 a0 = {0,0,0,0}, a1 = {0,0,0,0}, a2 = {0,0,0,0}, a3 = {0,0,0,0};
      const int rr = tr * 4;
      #pragma unroll
      for (int dd = 0; dd < 64; dd += 4) {
        float4 q0 = *(float4*)&qs[rr+0][dd], q1 = *(float4*)&qs[rr+1][dd];
        float4 q2 = *(float4*)&qs[rr+2][dd], q3 = *(float4*)&qs[rr+3][dd];
        float4 k0 = *(float4*)&kv[dd+0][c4], k1 = *(float4*)&kv[dd+1][c4];
        float4 k2 = *(float4*)&kv[dd+2][c4], k3 = *(float4*)&kv[dd+3][c4];
        fma4(a0, q0.x, k0); fma4(a0, q0.y, k1); fma4(a0, q0.z, k2); fma4(a0, q0.w, k3);
        fma4(a1, q1.x, k0); fma4(a1, q1.y, k1); fma4(a1, q1.z, k2); fma4(a1, q1.w, k3);
        fma4(a2, q2.x, k0); fma4(a2, q2.y, k1); fma4(a2, q2.z, k2); fma4(a2, q2.w, k3);
        fma4(a3, q3.x, k0); fma4(a3, q3.y, k1); fma4(a3, q3.z, k2); fma4(a3, q3.w, k3);
      }
      a0.x*=0.125f;a0.y*=0.125f;a0.z*=0.125f;a0.w*=0.125f;
      a1.x*=0.125f;a1.y*=0.125f;a1.z*=0.125f;a1.w*=0.125f;
      a2.x*=0.125f;a2.y*=0.125f;a2.z*=0.125f;a2.w*=0.125f;
      a3.x*=0.125f;a3.y*=0.125f;a3.z*=0.125f;a3.w*=0.125f;
      *(float4*)&sb[rr+0][c4] = a0; *(float4*)&sb[rr+1][c4] = a1;
      *(float4*)&sb[rr+2][c4] = a2; *(float4*)&sb[rr+3][c4] = a3;
    }
    __syncthreads();
    // stage V row-major [key][d] (coalesced), then phase B on sb
    #pragma unroll
    for (int c = 0; c < 4; ++c) {
      int f = t + 256 * c; int j = f >> 4, d4 = (f & 15) * 4;
      *(float4*)&kv[j][d4] = ld4f(&V[kbase + (size_t)j * 768 + d4]);
    }
    // phase B: online softmax
    if (heavy) {
      int row = t >> 4, g = t & 15;
      float4 s = *(float4*)&sb[row][g * 4];
      float mx = fmaxf(fmaxf(s.x, s.y), fmaxf(s.z, s.w));
      #pragma unroll
      for (int m = 1; m < 16; m <<= 1) mx = fmaxf(mx, __shfl_xor(mx, m, 64));
      float m_old = mrow[row];
      float mxn = fmaxf(mx, m_old);
      s.x = expf(s.x - mxn); s.y = expf(s.y - mxn);
      s.z = expf(s.z - mxn); s.w = expf(s.w - mxn);
      *(float4*)&sb[row][g * 4] = s;
      float sum = s.x + s.y + s.z + s.w;
      #pragma unroll
      for (int m = 1; m < 16; m <<= 1) sum += __shfl_xor(sum, m, 64);
      if (g == 0) {
        float c_ = expf(m_old - mxn);
        crow[row] = c_; lrow[row] = lrow[row] * c_ + sum; mrow[row] = mxn;
      }
    } else {
      int row = t >> 2, g = t & 3, j0 = g * 16;
      float4 s0 = *(float4*)&sb[row][j0+0],  s1 = *(float4*)&sb[row][j0+4];
      float4 s2 = *(float4*)&sb[row][j0+8],  s3 = *(float4*)&sb[row][j0+12];
      float mx = fmaxf(fmaxf(fmaxf(s0.x,s0.y),fmaxf(s0.z,s0.w)),
                       fmaxf(fmaxf(s1.x,s1.y),fmaxf(s1.z,s1.w)));
      mx = fmaxf(mx, fmaxf(fmaxf(fmaxf(s2.x,s2.y),fmaxf(s2.z,s2.w)),
                           fmaxf(fmaxf(s3.x,s3.y),fmaxf(s3.z,s3.w))));
      mx = fmaxf(mx, __shfl_xor(mx, 1, 64));
      mx = fmaxf(mx, __shfl_xor(mx, 2, 64));
      float m_old = mrow[row];
      float mxn = fmaxf(mx, m_old);
      s0.x=expf(s0.x-mxn); s0.y=expf(s0.y-mxn); s0.z=expf(s0.z-mxn); s0.w=expf(s0.w-mxn);
      s1.x=expf(s1.x-mxn); s1.y=expf(s1.y-mxn); s1.z=expf(s1.z-mxn); s1.w=expf(s1.w-mxn);
      s2.x=expf(s2.x-mxn); s2.y=expf(s2.y-mxn); s2.z=expf(s2.z-mxn); s2.w=expf(s2.w-mxn);
      s3.x=expf(s3.x-mxn); s3.y=expf(s3.y-mxn); s3.z=expf(s3.z-mxn); s3.w=expf(s3.w-mxn);
      *(float4*)&sb[row][j0+0] = s0; *(float4*)&sb[row][j0+4]  = s1;
      *(float4*)&sb[row][j0+8] = s2; *(float4*)&sb[row][j0+12] = s3;
      float sum = s0.x+s0.y+s0.z+s0.w + s1.x+s1.y+s1.z+s1.w
                + s2.x+s2.y+s2.z+s2.w + s3.x+s3.y+s3.z+s3.w;
      sum += __shfl_xor(sum, 1, 64);
      sum += __shfl_xor(sum, 2, 64);
      if (g == 0) {
        float c_ = expf(m_old - mxn);
        crow[row] = c_; lrow[row] = lrow[row] * c_ + sum; mrow[row] = mxn;
      }
    }
    __syncthreads();
    // phase C: O = O*c + P V
    if (heavy) {
      float cr = crow[tr];
      o0.x *= cr; o0.y *= cr; o0.z *= cr; o0.w *= cr;
      #pragma unroll
      for (int jb = 0; jb < 64; jb += 4) {
        float4 p  = *(float4*)&sb[tr][jb];
        float4 v0 = *(float4*)&kv[jb+0][c4], v1 = *(float4*)&kv[jb+1][c4];
        float4 v2 = *(float4*)&kv[jb+2][c4], v3 = *(float4*)&kv[jb+3][c4];
        fma4(o0, p.x, v0); fma4(o0, p.y, v1); fma4(o0, p.z, v2); fma4(o0, p.w, v3);
      }
    } else {
      const int rr = tr * 4;
      float cr0 = crow[rr], cr1 = crow[rr+1], cr2 = crow[rr+2], cr3 = crow[rr+3];
      o0.x*=cr0;o0.y*=cr0;o0.z*=cr0;o0.w*=cr0;
      o1.x*=cr1;o1.y*=cr1;o1.z*=cr1;o1.w*=cr1;
      o2.x*=cr2;o2.y*=cr2;o2.z*=cr2;o2.w*=cr2;
      o3.x*=cr3;o3.y*=cr3;o3.z*=cr3;o3.w*=cr3;
      #pragma unroll
      for (int jb = 0; jb < 64; jb += 4) {
        float4 p0 = *(float4*)&sb[rr+0][jb], p1 = *(float4*)&sb[rr+1][jb];
        float4 p2 = *(float4*)&sb[rr+2][jb], p3 = *(float4*)&sb[rr+3][jb];
        float4 v0 = *(float4*)&kv[jb+0][c4], v1 = *(float4*)&kv[jb+1][c4];
        float4 v2 = *(float4*)&kv[jb+2][c4], v3 = *(float4*)&kv[jb+3][c4];
        fma4(o0, p0.x, v0); fma4(o0, p0.y, v1); fma4(o0, p0.z, v2); fma4(o0, p0.w, v3);
        fma4(o1, p1.x, v0); fma4(o1, p1.y, v1); fma4(o1, p1.z, v2); fma4(o1, p1.w, v3);
        fma4(o2, p2.x, v0); fma4(o2, p2.y, v1); fma4(o2, p2.z, v2); fma4(o2, p2.w, v3);
        fma4(o3, p3.x, v0); fma4(o3, p3.y, v1); fma4(o3, p3.z, v2); fma4(o3, p3.w, v3);
      }
    }
    __syncthreads();
  }
  // normalize + write
  if (heavy) {
    float inv = 1.f / lrow[tr];
    float4 r = make_float4(o0.x*inv, o0.y*inv, o0.z*inv, o0.w*inv);
    *(float4*)&ctx[qbase + (size_t)(r0 + tr) * 768 + c4] = r;
  } else {
    const int rr = tr * 4;
    float i0 = 1.f/lrow[rr], i1 = 1.f/lrow[rr+1], i2 = 1.f/lrow[rr+2], i3 = 1.f/lrow[rr+3];
    *(float4*)&ctx[qbase + (size_t)(rr+0) * 768 + c4] = make_float4(o0.x*i0,o0.y*i0,o0.z*i0,o0.w*i0);
    *(float4*)&ctx[qbase + (size_t)(rr+1) * 768 + c4] = make_float4(o1.x*i1,o1.y*i1,o1.z*i1,o1.w*i1);
    *(float4*)&ctx[qbase + (size_t)(rr+2) * 768 + c4] = make_float4(o2.x*i2,o2.y*i2,o2.z*i2,o2.w*i2);
    *(float4*)&ctx[qbase + (size_t)(rr+3) * 768 + c4] = make_float4(o3.x*i3,o3.y*i3,o3.z*i3,o3.w*i3);
  }
}

// ---------------- LayerNorm(a + res) * g + b ----------------
template <typename TR, typename TO>
__global__ __launch_bounds__(256) void ln_kernel(
    const float* __restrict__ a, const TR* __restrict__ res,
    const float* __restrict__ g, const float* __restrict__ bb,
    TO* __restrict__ out)
{
  const int row = blockIdx.x, t = threadIdx.x;
  __shared__ float buf[768];
  __shared__ float rs[4], rss[4];
  const size_t base = (size_t)row * 768;
  float s = 0.f, ss = 0.f;
  for (int c = t; c < 768; c += 256) {
    float rv;
    if constexpr (sizeof(TR) == 2) rv = bf2f(res[base + c]);
    else                           rv = res[base + c];
    float v = a[base + c] + rv;
    buf[c] = v;
    s += v;
    ss = fmaf(v, v, ss);
  }
  #pragma unroll
  for (int off = 32; off > 0; off >>= 1) {
    s  += __shfl_down(s, off, 64);
    ss += __shfl_down(ss, off, 64);
  }
  if ((t & 63) == 0) { rs[t >> 6] = s; rss[t >> 6] = ss; }
  __syncthreads();
  float S  = rs[0] + rs[1] + rs[2] + rs[3];
  float SS = rss[0] + rss[1] + rss[2] + rss[3];
  float mu  = S * (1.f / 768.f);
  float var = SS * (1.f / 768.f) - mu * mu;
  float inv = rsqrtf(var + 1e-5f);
  for (int c = t; c < 768; c += 256) {
    float v = (buf[c] - mu) * inv * g[c] + bb[c];
    if constexpr (sizeof(TO) == 2) out[base + c] = f2bf(v);
    else                           out[base + c] = v;
  }
}

extern "C" void kernel_launch(void* const* d_in, const int* in_sizes, int n_in,
                              void* d_out, int out_size, void* d_ws, size_t ws_size,
                              hipStream_t stream)
{
  const float* x   = (const float*)d_in[0];
  const int*   rnd = (const int*)d_in[1];
  const float* Wq  = (const float*)d_in[2];
  const float* bq  = (const float*)d_in[3];
  const float* Wk  = (const float*)d_in[4];
  const float* bk  = (const float*)d_in[5];
  const float* Wv  = (const float*)d_in[6];
  const float* bv  = (const float*)d_in[7];
  const float* g1  = (const float*)d_in[8];
  const float* be1 = (const float*)d_in[9];
  const float* W1  = (const float*)d_in[10];
  const float* b1  = (const float*)d_in[11];
  const float* W2  = (const float*)d_in[12];
  const float* b2  = (const float*)d_in[13];
  const float* g2  = (const float*)d_in[14];
  const float* be2 = (const float*)d_in[15];
  float* out = (float*)d_out;

  const size_t MT = 8192;  // B*S rows
  bf* Kb  = (bf*)d_ws;           // 8192*768 bf16 (12.6 MB)
  bf* Vb  = Kb + MT * 768;       // 8192*768 bf16 (12.6 MB)
  float* Qb  = out;              // Q f32 in d_out; attn runs in-place
  float* ctx = out;
  bf* h1  = Kb;                  // reuses K slot after attention
  bf* f1c = Vb;                  // reuses V slot after attention
  float* f2 = out;               // FFN accumulator in d_out

  dim3 blk(256);
  dim3 g768(768 / 64, MT / 128);
  gemm_k<float, float><<<g768, blk, 0, stream>>>(x, Wq, bq, Qb, MT, 768, 768, 768, 0, 0);
  gemm_k<float, bf   ><<<g768, blk, 0, stream>>>(x, Wk, bk, Kb, MT, 768, 768, 768, 0, 0);
  gemm_k<float, bf   ><<<g768, blk, 0, stream>>>(x, Wv, bv, Vb, MT, 768, 768, 768, 0, 0);
  attn2_kernel<<<dim3(1680), blk, 0, stream>>>(Qb, Kb, Vb, rnd, ctx);
  ln_kernel<float, bf><<<dim3(MT), blk, 0, stream>>>(ctx, x, g1, be1, h1);
  // FFN in 4 chunks of 768 over the FF dimension; f2 (d_out) accumulates.
  for (int c = 0; c < 4; ++c) {
    gemm_k<bf, bf   ><<<g768, blk, 0, stream>>>(h1, W1 + c * 768, b1 + c * 768, f1c,
                                                MT, 768, 768, 3072, 1, 0);
    gemm_k<bf, float><<<g768, blk, 0, stream>>>(f1c, W2 + (size_t)c * 768 * 768,
                                                (c == 0 ? b2 : (const float*)nullptr), f2,
                                                MT, 768, 768, 768, 0, (c == 0 ? 0 : 1));
  }
  ln_kernel<bf, float><<<dim3(MT), blk, 0, stream>>>(f2, h1, g2, be2, out);
}

// Round 9
// 917.411 us; speedup vs baseline: 4.7737x; 2.2178x over previous
//
#include <hip/hip_runtime.h>
#include <cmath>

// B=2, S=4096, DM=768, H=12, FF=3072, BLOCK=64, NB=64, R=3, d=64
// Round 9: all GEMMs -> bf16 MFMA (16x16x32), f32 accumulate.
// Memory plan unchanged from round 8 (ws: K,V bf16 -> h1,f1c; d_out: Q/ctx/f2 f32).

typedef unsigned short bf;
typedef __attribute__((ext_vector_type(8))) short bf16x8;
typedef __attribute__((ext_vector_type(4))) float f32x4;

__device__ __forceinline__ float bf2f(bf u) { return __uint_as_float(((unsigned)u) << 16); }
__device__ __forceinline__ bf f2bf(float f) {
  unsigned x = __float_as_uint(f);
  x += 0x7FFFu + ((x >> 16) & 1u);   // round-to-nearest-even
  return (bf)(x >> 16);
}

__device__ __forceinline__ float4 ld4f(const float* p) { return *(const float4*)p; }
__device__ __forceinline__ float4 ld4f(const bf* p) {
  ushort4 u = *(const ushort4*)p;
  return make_float4(bf2f(u.x), bf2f(u.y), bf2f(u.z), bf2f(u.w));
}
__device__ __forceinline__ void fma4(float4& a, float s, const float4& v) {
  a.x = fmaf(s, v.x, a.x); a.y = fmaf(s, v.y, a.y);
  a.z = fmaf(s, v.z, a.z); a.w = fmaf(s, v.w, a.w);
}

// ---- MFMA GEMM: C = [beta*C] + A(MxK)*B(K x N, row stride ldb) [+bias] [GELU]
// tile 128x64, BK=64, 256 threads (4 waves 2x2), per-wave 64x32 out.
// A LDS [row][k] bf16, swizzle byte^=(row&7)<<4 ; B LDS [col][k] bf16, same swizzle.
template <typename TA, typename TC>
__global__ __launch_bounds__(256) void mgemm_k(
    const TA* __restrict__ A, const float* __restrict__ B,
    const float* __restrict__ bias, TC* __restrict__ C,
    int M, int N, int K, int ldb, int ep, int beta)
{
  __shared__ char smem[24576];          // A: 16384 B, B: 8192 B
  char* sA = smem;
  char* sB = smem + 16384;
  const int t = threadIdx.x;
  const int bm = blockIdx.y * 128, bn = blockIdx.x * 64;
  const int lane = t & 63, wid = t >> 6;
  const int wm = wid >> 1, wn = wid & 1;
  const int fr = lane & 15, fq = lane >> 4;

  f32x4 acc[4][2];
  #pragma unroll
  for (int i = 0; i < 4; ++i)
    #pragma unroll
    for (int j = 0; j < 2; ++j) acc[i][j] = (f32x4){0.f, 0.f, 0.f, 0.f};

  const int bcol = t & 63, bkq = t >> 6;   // B staging coords

  for (int k0 = 0; k0 < K; k0 += 64) {
    // ---- stage A: 128 rows x 64 k, 4 chunks of 8 bf16 per thread ----
    #pragma unroll
    for (int c = 0; c < 4; ++c) {
      int id = t + 256 * c;
      int row = id >> 3, kc = (id & 7) * 8;
      ushort4 lo, hi;
      if constexpr (sizeof(TA) == 4) {
        const float* ap = &A[(size_t)(bm + row) * K + k0 + kc];
        float4 f0 = *(const float4*)ap;
        float4 f1 = *(const float4*)(ap + 4);
        lo = make_ushort4(f2bf(f0.x), f2bf(f0.y), f2bf(f0.z), f2bf(f0.w));
        hi = make_ushort4(f2bf(f1.x), f2bf(f1.y), f2bf(f1.z), f2bf(f1.w));
      } else {
        const bf* ap = &A[(size_t)(bm + row) * K + k0 + kc];
        lo = *(const ushort4*)ap;
        hi = *(const ushort4*)(ap + 4);
      }
      int off = row * 128 + ((kc * 2) ^ ((row & 7) << 4));
      *(ushort4*)(sA + off)     = lo;
      *(ushort4*)(sA + off + 8) = hi;
    }
    // ---- stage B transposed: [col][k], 16 k per thread in 4 groups of 4 ----
    #pragma unroll
    for (int q = 0; q < 4; ++q) {
      int k = bkq * 16 + q * 4;
      const float* bp = &B[(size_t)(k0 + k) * ldb + bn + bcol];
      float b0 = bp[0];
      float b1 = bp[ldb];
      float b2 = bp[2 * (size_t)ldb];
      float b3 = bp[3 * (size_t)ldb];
      ushort4 pk = make_ushort4(f2bf(b0), f2bf(b1), f2bf(b2), f2bf(b3));
      int off = bcol * 128 + ((k * 2) ^ ((bcol & 7) << 4));
      *(ushort4*)(sB + off) = pk;
    }
    __syncthreads();
    // ---- MFMA: 2 k-halves x 4 m-tiles x 2 n-tiles ----
    #pragma unroll
    for (int kk = 0; kk < 2; ++kk) {
      const int kb = (kk * 32 + fq * 8) * 2;
      bf16x8 a[4], b[2];
      #pragma unroll
      for (int i = 0; i < 4; ++i) {
        int row = wm * 64 + i * 16 + fr;
        a[i] = *(const bf16x8*)(sA + row * 128 + (kb ^ ((row & 7) << 4)));
      }
      #pragma unroll
      for (int j = 0; j < 2; ++j) {
        int col = wn * 32 + j * 16 + fr;
        b[j] = *(const bf16x8*)(sB + col * 128 + (kb ^ ((col & 7) << 4)));
      }
      #pragma unroll
      for (int i = 0; i < 4; ++i)
        #pragma unroll
        for (int j = 0; j < 2; ++j)
          acc[i][j] = __builtin_amdgcn_mfma_f32_16x16x32_bf16(a[i], b[j], acc[i][j], 0, 0, 0);
    }
    __syncthreads();
  }
  // ---- epilogue ----
  #pragma unroll
  for (int j = 0; j < 2; ++j) {
    int col = bn + wn * 32 + j * 16 + fr;
    float bias_v = bias ? bias[col] : 0.f;
    #pragma unroll
    for (int i = 0; i < 4; ++i) {
      int row0 = bm + wm * 64 + i * 16 + fq * 4;
      #pragma unroll
      for (int r = 0; r < 4; ++r) {
        size_t idx = (size_t)(row0 + r) * N + col;
        float v = acc[i][j][r] + bias_v;
        if (ep == 1) v = 0.5f * v * (1.0f + erff(v * 0.70710678118654752f));
        if (beta) {
          if constexpr (sizeof(TC) == 2) v += bf2f(C[idx]);
          else                           v += C[idx];
        }
        if constexpr (sizeof(TC) == 2) C[idx] = f2bf(v);
        else                           C[idx] = v;
      }
    }
  }
}

// ---------------- BigBird attention v2 (unchanged from round 8) ----------------
__global__ __launch_bounds__(256) void attn2_kernel(
    const float* __restrict__ Q, const bf* __restrict__ K,
    const bf* __restrict__ V, const int* __restrict__ rnd,
    float* __restrict__ ctx)
{
  __shared__ float qs[64][68];
  __shared__ float kv[64][68];
  __shared__ float sb[64][68];
  __shared__ float mrow[64], lrow[64], crow[64];
  __shared__ int klist[8];
  const int t = threadIdx.x;
  const int wg = blockIdx.x;
  const bool heavy = wg < 192;
  int b, h, n, r0 = 0, nkb;
  if (heavy) {
    int chunk = wg & 3;
    n = ((wg >> 2) & 1) ? 63 : 0;
    int bh = wg >> 3;  h = bh % 12;  b = bh / 12;
    r0 = chunk * 16;  nkb = 64;
  } else {
    int idx = wg - 192;
    n = 1 + idx % 62;
    int bh = idx / 62;  h = bh % 12;  b = bh / 12;
    nkb = (n == 1 || n == 62) ? 7 : 8;
    if (t == 0) {
      int cnt = 0;
      if (n == 1)       { klist[cnt++] = 0; klist[cnt++] = 1;  klist[cnt++] = 2;  klist[cnt++] = 63; }
      else if (n == 62) { klist[cnt++] = 0; klist[cnt++] = 61; klist[cnt++] = 62; klist[cnt++] = 63; }
      else              { klist[cnt++] = 0; klist[cnt++] = n - 1; klist[cnt++] = n; klist[cnt++] = n + 1; }
      for (int j = 0; j < 3; ++j) klist[cnt++] = rnd[(h * 62 + (n - 1)) * 3 + j];
      if (n != 1 && n != 62) klist[cnt++] = 63;
    }
  }
  const size_t qbase = ((size_t)b * 4096 + (size_t)n * 64) * 768 + h * 64;
  const int tr = t >> 4, tc = t & 15, c4 = tc * 4;

  if (heavy) {
    *(float4*)&qs[tr][c4] = ld4f(&Q[qbase + (size_t)(r0 + tr) * 768 + c4]);
  } else {
    #pragma unroll
    for (int c = 0; c < 4; ++c) {
      int f = t + 256 * c; int row = f >> 4, cc = (f & 15) * 4;
      *(float4*)&qs[row][cc] = ld4f(&Q[qbase + (size_t)row * 768 + cc]);
    }
  }
  if (t < 64) { mrow[t] = -1e30f; lrow[t] = 0.f; }
  float4 o0 = {0,0,0,0}, o1 = {0,0,0,0}, o2 = {0,0,0,0}, o3 = {0,0,0,0};
  __syncthreads();

  for (int ib = 0; ib < nkb; ++ib) {
    const int kb = heavy ? ib : klist[ib];
    const size_t kbase = ((size_t)b * 4096 + (size_t)kb * 64) * 768 + h * 64;
    {
      int j = t & 63, db = (t >> 6) * 16;
      const bf* kp = &K[kbase + (size_t)j * 768 + db];
      #pragma unroll
      for (int u = 0; u < 4; ++u) {
        ushort4 uv = *(const ushort4*)(kp + u * 4);
        kv[db + u*4 + 0][j] = bf2f(uv.x); kv[db + u*4 + 1][j] = bf2f(uv.y);
        kv[db + u*4 + 2][j] = bf2f(uv.z); kv[db + u*4 + 3][j] = bf2f(uv.w);
      }
    }
    __syncthreads();
    if (heavy) {
      float4 acc = {0,0,0,0};
      #pragma unroll
      for (int dd = 0; dd < 64; dd += 4) {
        float4 q  = *(float4*)&qs[tr][dd];
        float4 k0 = *(float4*)&kv[dd+0][c4], k1 = *(float4*)&kv[dd+1][c4];
        float4 k2 = *(float4*)&kv[dd+2][c4], k3 = *(float4*)&kv[dd+3][c4];
        fma4(acc, q.x, k0); fma4(acc, q.y, k1); fma4(acc, q.z, k2); fma4(acc, q.w, k3);
      }
      acc.x *= 0.125f; acc.y *= 0.125f; acc.z *= 0.125f; acc.w *= 0.125f;
      *(float4*)&sb[tr][c4] = acc;
    } else {
      float4 a0 = {0,0,0,0}, a1 = {0,0,0,0}, a2 = {0,0,0,0}, a3 = {0,0,0,0};
      const int rr = tr * 4;
      #pragma unroll
      for (int dd = 0; dd < 64; dd += 4) {
        float4 q0 = *(float4*)&qs[rr+0][dd], q1 = *(float4*)&qs[rr+1][dd];
        float4 q2 = *(float4*)&qs[rr+2][dd], q3 = *(float4*)&qs[rr+3][dd];
        float4 k0 = *(float4*)&kv[dd+0][c4], k1 = *(float4*)&kv[dd+1][c4];
        float4 k2 = *(float4*)&kv[dd+2][c4], k3 = *(float4*)&kv[dd+3][c4];
        fma4(a0, q0.x, k0); fma4(a0, q0.y, k1); fma4(a0, q0.z, k2); fma4(a0, q0.w, k3);
        fma4(a1, q1.x, k0); fma4(a1, q1.y, k1); fma4(a1, q1.z, k2); fma4(a1, q1.w, k3);
        fma4(a2, q2.x, k0); fma4(a2, q2.y, k1); fma4(a2, q2.z, k2); fma4(a2, q2.w, k3);
        fma4(a3, q3.x, k0); fma4(a3, q3.y, k1); fma4(a3, q3.z, k2); fma4(a3, q3.w, k3);
      }
      a0.x*=0.125f;a0.y*=0.125f;a0.z*=0.125f;a0.w*=0.125f;
      a1.x*=0.125f;a1.y*=0.125f;a1.z*=0.125f;a1.w*=0.125f;
      a2.x*=0.125f;a2.y*=0.125f;a2.z*=0.125f;a2.w*=0.125f;
      a3.x*=0.125f;a3.y*=0.125f;a3.z*=0.125f;a3.w*=0.125f;
      *(float4*)&sb[rr+0][c4] = a0; *(float4*)&sb[rr+1][c4] = a1;
      *(float4*)&sb[rr+2][c4] = a2; *(float4*)&sb[rr+3][c4] = a3;
    }
    __syncthreads();
    #pragma unroll
    for (int c = 0; c < 4; ++c) {
      int f = t + 256 * c; int j = f >> 4, d4 = (f & 15) * 4;
      *(float4*)&kv[j][d4] = ld4f(&V[kbase + (size_t)j * 768 + d4]);
    }
    if (heavy) {
      int row = t >> 4, g = t & 15;
      float4 s = *(float4*)&sb[row][g * 4];
      float mx = fmaxf(fmaxf(s.x, s.y), fmaxf(s.z, s.w));
      #pragma unroll
      for (int m = 1; m < 16; m <<= 1) mx = fmaxf(mx, __shfl_xor(mx, m, 64));
      float m_old = mrow[row];
      float mxn = fmaxf(mx, m_old);
      s.x = expf(s.x - mxn); s.y = expf(s.y - mxn);
      s.z = expf(s.z - mxn); s.w = expf(s.w - mxn);
      *(float4*)&sb[row][g * 4] = s;
      float sum = s.x + s.y + s.z + s.w;
      #pragma unroll
      for (int m = 1; m < 16; m <<= 1) sum += __shfl_xor(sum, m, 64);
      if (g == 0) {
        float c_ = expf(m_old - mxn);
        crow[row] = c_; lrow[row] = lrow[row] * c_ + sum; mrow[row] = mxn;
      }
    } else {
      int row = t >> 2, g = t & 3, j0 = g * 16;
      float4 s0 = *(float4*)&sb[row][j0+0],  s1 = *(float4*)&sb[row][j0+4];
      float4 s2 = *(float4*)&sb[row][j0+8],  s3 = *(float4*)&sb[row][j0+12];
      float mx = fmaxf(fmaxf(fmaxf(s0.x,s0.y),fmaxf(s0.z,s0.w)),
                       fmaxf(fmaxf(s1.x,s1.y),fmaxf(s1.z,s1.w)));
      mx = fmaxf(mx, fmaxf(fmaxf(fmaxf(s2.x,s2.y),fmaxf(s2.z,s2.w)),
                           fmaxf(fmaxf(s3.x,s3.y),fmaxf(s3.z,s3.w))));
      mx = fmaxf(mx, __shfl_xor(mx, 1, 64));
      mx = fmaxf(mx, __shfl_xor(mx, 2, 64));
      float m_old = mrow[row];
      float mxn = fmaxf(mx, m_old);
      s0.x=expf(s0.x-mxn); s0.y=expf(s0.y-mxn); s0.z=expf(s0.z-mxn); s0.w=expf(s0.w-mxn);
      s1.x=expf(s1.x-mxn); s1.y=expf(s1.y-mxn); s1.z=expf(s1.z-mxn); s1.w=expf(s1.w-mxn);
      s2.x=expf(s2.x-mxn); s2.y=expf(s2.y-mxn); s2.z=expf(s2.z-mxn); s2.w=expf(s2.w-mxn);
      s3.x=expf(s3.x-mxn); s3.y=expf(s3.y-mxn); s3.z=expf(s3.z-mxn); s3.w=expf(s3.w-mxn);
      *(float4*)&sb[row][j0+0] = s0; *(float4*)&sb[row][j0+4]  = s1;
      *(float4*)&sb[row][j0+8] = s2; *(float4*)&sb[row][j0+12] = s3;
      float sum = s0.x+s0.y+s0.z+s0.w + s1.x+s1.y+s1.z+s1.w
                + s2.x+s2.y+s2.z+s2.w + s3.x+s3.y+s3.z+s3.w;
      sum += __shfl_xor(sum, 1, 64);
      sum += __shfl_xor(sum, 2, 64);
      if (g == 0) {
        float c_ = expf(m_old - mxn);
        crow[row] = c_; lrow[row] = lrow[row] * c_ + sum; mrow[row] = mxn;
      }
    }
    __syncthreads();
    if (heavy) {
      float cr = crow[tr];
      o0.x *= cr; o0.y *= cr; o0.z *= cr; o0.w *= cr;
      #pragma unroll
      for (int jb = 0; jb < 64; jb += 4) {
        float4 p  = *(float4*)&sb[tr][jb];
        float4 v0 = *(float4*)&kv[jb+0][c4], v1 = *(float4*)&kv[jb+1][c4];
        float4 v2 = *(float4*)&kv[jb+2][c4], v3 = *(float4*)&kv[jb+3][c4];
        fma4(o0, p.x, v0); fma4(o0, p.y, v1); fma4(o0, p.z, v2); fma4(o0, p.w, v3);
      }
    } else {
      const int rr = tr * 4;
      float cr0 = crow[rr], cr1 = crow[rr+1], cr2 = crow[rr+2], cr3 = crow[rr+3];
      o0.x*=cr0;o0.y*=cr0;o0.z*=cr0;o0.w*=cr0;
      o1.x*=cr1;o1.y*=cr1;o1.z*=cr1;o1.w*=cr1;
      o2.x*=cr2;o2.y*=cr2;o2.z*=cr2;o2.w*=cr2;
      o3.x*=cr3;o3.y*=cr3;o3.z*=cr3;o3.w*=cr3;
      #pragma unroll
      for (int jb = 0; jb < 64; jb += 4) {
        float4 p0 = *(float4*)&sb[rr+0][jb], p1 = *(float4*)&sb[rr+1][jb];
        float4 p2 = *(float4*)&sb[rr+2][jb], p3 = *(float4*)&sb[rr+3][jb];
        float4 v0 = *(float4*)&kv[jb+0][c4], v1 = *(float4*)&kv[jb+1][c4];
        float4 v2 = *(float4*)&kv[jb+2][c4], v3 = *(float4*)&kv[jb+3][c4];
        fma4(o0, p0.x, v0); fma4(o0, p0.y, v1); fma4(o0, p0.z, v2); fma4(o0, p0.w, v3);
        fma4(o1, p1.x, v0); fma4(o1, p1.y, v1); fma4(o1, p1.z, v2); fma4(o1, p1.w, v3);
        fma4(o2, p2.x, v0); fma4(o2, p2.y, v1); fma4(o2, p2.z, v2); fma4(o2, p2.w, v3);
        fma4(o3, p3.x, v0); fma4(o3, p3.y, v1); fma4(o3, p3.z, v2); fma4(o3, p3.w, v3);
      }
    }
    __syncthreads();
  }
  if (heavy) {
    float inv = 1.f / lrow[tr];
    float4 r = make_float4(o0.x*inv, o0.y*inv, o0.z*inv, o0.w*inv);
    *(float4*)&ctx[qbase + (size_t)(r0 + tr) * 768 + c4] = r;
  } else {
    const int rr = tr * 4;
    float i0 = 1.f/lrow[rr], i1 = 1.f/lrow[rr+1], i2 = 1.f/lrow[rr+2], i3 = 1.f/lrow[rr+3];
    *(float4*)&ctx[qbase + (size_t)(rr+0) * 768 + c4] = make_float4(o0.x*i0,o0.y*i0,o0.z*i0,o0.w*i0);
    *(float4*)&ctx[qbase + (size_t)(rr+1) * 768 + c4] = make_float4(o1.x*i1,o1.y*i1,o1.z*i1,o1.w*i1);
    *(float4*)&ctx[qbase + (size_t)(rr+2) * 768 + c4] = make_float4(o2.x*i2,o2.y*i2,o2.z*i2,o2.w*i2);
    *(float4*)&ctx[qbase + (size_t)(rr+3) * 768 + c4] = make_float4(o3.x*i3,o3.y*i3,o3.z*i3,o3.w*i3);
  }
}

// ---------------- LayerNorm(a + res) * g + b ----------------
template <typename TR, typename TO>
__global__ __launch_bounds__(256) void ln_kernel(
    const float* __restrict__ a, const TR* __restrict__ res,
    const float* __restrict__ g, const float* __restrict__ bb,
    TO* __restrict__ out)
{
  const int row = blockIdx.x, t = threadIdx.x;
  __shared__ float buf[768];
  __shared__ float rs[4], rss[4];
  const size_t base = (size_t)row * 768;
  float s = 0.f, ss = 0.f;
  for (int c = t; c < 768; c += 256) {
    float rv;
    if constexpr (sizeof(TR) == 2) rv = bf2f(res[base + c]);
    else                           rv = res[base + c];
    float v = a[base + c] + rv;
    buf[c] = v;
    s += v;
    ss = fmaf(v, v, ss);
  }
  #pragma unroll
  for (int off = 32; off > 0; off >>= 1) {
    s  += __shfl_down(s, off, 64);
    ss += __shfl_down(ss, off, 64);
  }
  if ((t & 63) == 0) { rs[t >> 6] = s; rss[t >> 6] = ss; }
  __syncthreads();
  float S  = rs[0] + rs[1] + rs[2] + rs[3];
  float SS = rss[0] + rss[1] + rss[2] + rss[3];
  float mu  = S * (1.f / 768.f);
  float var = SS * (1.f / 768.f) - mu * mu;
  float inv = rsqrtf(var + 1e-5f);
  for (int c = t; c < 768; c += 256) {
    float v = (buf[c] - mu) * inv * g[c] + bb[c];
    if constexpr (sizeof(TO) == 2) out[base + c] = f2bf(v);
    else                           out[base + c] = v;
  }
}

extern "C" void kernel_launch(void* const* d_in, const int* in_sizes, int n_in,
                              void* d_out, int out_size, void* d_ws, size_t ws_size,
                              hipStream_t stream)
{
  const float* x   = (const float*)d_in[0];
  const int*   rnd = (const int*)d_in[1];
  const float* Wq  = (const float*)d_in[2];
  const float* bq  = (const float*)d_in[3];
  const float* Wk  = (const float*)d_in[4];
  const float* bk  = (const float*)d_in[5];
  const float* Wv  = (const float*)d_in[6];
  const float* bv  = (const float*)d_in[7];
  const float* g1  = (const float*)d_in[8];
  const float* be1 = (const float*)d_in[9];
  const float* W1  = (const float*)d_in[10];
  const float* b1  = (const float*)d_in[11];
  const float* W2  = (const float*)d_in[12];
  const float* b2  = (const float*)d_in[13];
  const float* g2  = (const float*)d_in[14];
  const float* be2 = (const float*)d_in[15];
  float* out = (float*)d_out;

  const size_t MT = 8192;  // B*S rows
  bf* Kb  = (bf*)d_ws;           // 8192*768 bf16 (12.6 MB)
  bf* Vb  = Kb + MT * 768;       // 8192*768 bf16 (12.6 MB)
  float* Qb  = out;              // Q f32 in d_out; attn runs in-place
  float* ctx = out;
  bf* h1  = Kb;                  // reuses K slot after attention
  bf* f1c = Vb;                  // reuses V slot after attention
  float* f2 = out;               // FFN accumulator in d_out

  dim3 blk(256);
  dim3 g768(768 / 64, MT / 128);
  mgemm_k<float, float><<<g768, blk, 0, stream>>>(x, Wq, bq, Qb, MT, 768, 768, 768, 0, 0);
  mgemm_k<float, bf   ><<<g768, blk, 0, stream>>>(x, Wk, bk, Kb, MT, 768, 768, 768, 0, 0);
  mgemm_k<float, bf   ><<<g768, blk, 0, stream>>>(x, Wv, bv, Vb, MT, 768, 768, 768, 0, 0);
  attn2_kernel<<<dim3(1680), blk, 0, stream>>>(Qb, Kb, Vb, rnd, ctx);
  ln_kernel<float, bf><<<dim3(MT), blk, 0, stream>>>(ctx, x, g1, be1, h1);
  // FFN in 4 chunks of 768 over the FF dimension; f2 (d_out) accumulates.
  for (int c = 0; c < 4; ++c) {
    mgemm_k<bf, bf   ><<<g768, blk, 0, stream>>>(h1, W1 + c * 768, b1 + c * 768, f1c,
                                                 MT, 768, 768, 3072, 1, 0);
    mgemm_k<bf, float><<<g768, blk, 0, stream>>>(f1c, W2 + (size_t)c * 768 * 768,
                                                 (c == 0 ? b2 : (const float*)nullptr), f2,
                                                 MT, 768, 768, 768, 0, (c == 0 ? 0 : 1));
  }
  ln_kernel<bf, float><<<dim3(MT), blk, 0, stream>>>(f2, h1, g2, be2, out);
}

// Round 10
// 725.963 us; speedup vs baseline: 6.0326x; 1.2637x over previous
//
#include <hip/hip_runtime.h>
#include <cmath>

// B=2, S=4096, DM=768, H=12, FF=3072, BLOCK=64, NB=64, R=3, d=64
// Round 10: attention -> MFMA bf16 (attn3). GEMM/LN unchanged from round 9.
// ws: K,V bf16 -> h1,f1c; d_out: Q f32 -> ctx (in-place) -> f2 -> out.

typedef unsigned short bf;
typedef __attribute__((ext_vector_type(8))) short bf16x8;
typedef __attribute__((ext_vector_type(4))) float f32x4;

__device__ __forceinline__ float bf2f(bf u) { return __uint_as_float(((unsigned)u) << 16); }
__device__ __forceinline__ bf f2bf(float f) {
  unsigned x = __float_as_uint(f);
  x += 0x7FFFu + ((x >> 16) & 1u);   // round-to-nearest-even
  return (bf)(x >> 16);
}
__device__ __forceinline__ float4 ld4f(const float* p) { return *(const float4*)p; }
__device__ __forceinline__ float4 ld4f(const bf* p) {
  ushort4 u = *(const ushort4*)p;
  return make_float4(bf2f(u.x), bf2f(u.y), bf2f(u.z), bf2f(u.w));
}

// ---- MFMA GEMM (verified round 9): C = [beta*C] + A*B [+bias] [GELU] ----
template <typename TA, typename TC>
__global__ __launch_bounds__(256) void mgemm_k(
    const TA* __restrict__ A, const float* __restrict__ B,
    const float* __restrict__ bias, TC* __restrict__ C,
    int M, int N, int K, int ldb, int ep, int beta)
{
  __shared__ char smem[24576];
  char* sA = smem;
  char* sB = smem + 16384;
  const int t = threadIdx.x;
  const int bm = blockIdx.y * 128, bn = blockIdx.x * 64;
  const int lane = t & 63, wid = t >> 6;
  const int wm = wid >> 1, wn = wid & 1;
  const int fr = lane & 15, fq = lane >> 4;

  f32x4 acc[4][2];
  #pragma unroll
  for (int i = 0; i < 4; ++i)
    #pragma unroll
    for (int j = 0; j < 2; ++j) acc[i][j] = (f32x4){0.f, 0.f, 0.f, 0.f};

  const int bcol = t & 63, bkq = t >> 6;

  for (int k0 = 0; k0 < K; k0 += 64) {
    #pragma unroll
    for (int c = 0; c < 4; ++c) {
      int id = t + 256 * c;
      int row = id >> 3, kc = (id & 7) * 8;
      ushort4 lo, hi;
      if constexpr (sizeof(TA) == 4) {
        const float* ap = &A[(size_t)(bm + row) * K + k0 + kc];
        float4 f0 = *(const float4*)ap;
        float4 f1 = *(const float4*)(ap + 4);
        lo = make_ushort4(f2bf(f0.x), f2bf(f0.y), f2bf(f0.z), f2bf(f0.w));
        hi = make_ushort4(f2bf(f1.x), f2bf(f1.y), f2bf(f1.z), f2bf(f1.w));
      } else {
        const bf* ap = &A[(size_t)(bm + row) * K + k0 + kc];
        lo = *(const ushort4*)ap;
        hi = *(const ushort4*)(ap + 4);
      }
      int off = row * 128 + ((kc * 2) ^ ((row & 7) << 4));
      *(ushort4*)(sA + off)     = lo;
      *(ushort4*)(sA + off + 8) = hi;
    }
    #pragma unroll
    for (int q = 0; q < 4; ++q) {
      int k = bkq * 16 + q * 4;
      const float* bp = &B[(size_t)(k0 + k) * ldb + bn + bcol];
      float b0 = bp[0];
      float b1 = bp[ldb];
      float b2 = bp[2 * (size_t)ldb];
      float b3 = bp[3 * (size_t)ldb];
      ushort4 pk = make_ushort4(f2bf(b0), f2bf(b1), f2bf(b2), f2bf(b3));
      int off = bcol * 128 + ((k * 2) ^ ((bcol & 7) << 4));
      *(ushort4*)(sB + off) = pk;
    }
    __syncthreads();
    #pragma unroll
    for (int kk = 0; kk < 2; ++kk) {
      const int kb = (kk * 32 + fq * 8) * 2;
      bf16x8 a[4], b[2];
      #pragma unroll
      for (int i = 0; i < 4; ++i) {
        int row = wm * 64 + i * 16 + fr;
        a[i] = *(const bf16x8*)(sA + row * 128 + (kb ^ ((row & 7) << 4)));
      }
      #pragma unroll
      for (int j = 0; j < 2; ++j) {
        int col = wn * 32 + j * 16 + fr;
        b[j] = *(const bf16x8*)(sB + col * 128 + (kb ^ ((col & 7) << 4)));
      }
      #pragma unroll
      for (int i = 0; i < 4; ++i)
        #pragma unroll
        for (int j = 0; j < 2; ++j)
          acc[i][j] = __builtin_amdgcn_mfma_f32_16x16x32_bf16(a[i], b[j], acc[i][j], 0, 0, 0);
    }
    __syncthreads();
  }
  #pragma unroll
  for (int j = 0; j < 2; ++j) {
    int col = bn + wn * 32 + j * 16 + fr;
    float bias_v = bias ? bias[col] : 0.f;
    #pragma unroll
    for (int i = 0; i < 4; ++i) {
      int row0 = bm + wm * 64 + i * 16 + fq * 4;
      #pragma unroll
      for (int r = 0; r < 4; ++r) {
        size_t idx = (size_t)(row0 + r) * N + col;
        float v = acc[i][j][r] + bias_v;
        if (ep == 1) v = 0.5f * v * (1.0f + erff(v * 0.70710678118654752f));
        if (beta) {
          if constexpr (sizeof(TC) == 2) v += bf2f(C[idx]);
          else                           v += C[idx];
        }
        if constexpr (sizeof(TC) == 2) C[idx] = f2bf(v);
        else                           C[idx] = v;
      }
    }
  }
}

// ---------------- BigBird attention v3: MFMA bf16 ----------------
// One WG (4 waves) per (b,h,qblock). Wave w owns q-rows w*16..w*16+15.
// sQP: Q bf16 (pre-scaled 0.125), then reused for P. sK: [key][d]. sVT: [d][key].
__global__ __launch_bounds__(256) void attn3_kernel(
    const float* __restrict__ Q, const bf* __restrict__ K,
    const bf* __restrict__ V, const int* __restrict__ rnd,
    float* __restrict__ ctx)
{
  __shared__ char sQP[8192];
  __shared__ char sK[8192];
  __shared__ char sVT[8192];
  __shared__ int klist[8];
  const int t = threadIdx.x;
  const int lane = t & 63, w = t >> 6;
  const int fr = lane & 15, fq = lane >> 4;
  const int wg = blockIdx.x;
  const int n = wg & 63;
  const int h = (wg >> 6) % 12;
  const int b = wg / 768;
  int nkb;
  if (n == 0 || n == 63) {
    nkb = 64;
  } else {
    nkb = (n == 1 || n == 62) ? 7 : 8;
    if (t == 0) {
      int cnt = 0;
      if (n == 1)       { klist[0]=0; klist[1]=1;  klist[2]=2;  klist[3]=63; cnt=4; }
      else if (n == 62) { klist[0]=0; klist[1]=61; klist[2]=62; klist[3]=63; cnt=4; }
      else              { klist[0]=0; klist[1]=n-1; klist[2]=n; klist[3]=n+1; cnt=4; }
      for (int j = 0; j < 3; ++j) klist[cnt++] = rnd[(h * 62 + (n - 1)) * 3 + j];
      if (n != 1 && n != 62) klist[cnt++] = 63;
    }
  }
  const size_t qbase = ((size_t)b * 4096 + (size_t)n * 64) * 768 + h * 64;

  // stage Q -> bf16, pre-scaled by 1/8 (folds QK^T scale)
  {
    int row = t >> 2, d0 = (t & 3) * 16;
    const float* qp = &Q[qbase + (size_t)row * 768 + d0];
    #pragma unroll
    for (int i = 0; i < 2; ++i) {
      float4 f0 = *(const float4*)(qp + 8 * i);
      float4 f1 = *(const float4*)(qp + 8 * i + 4);
      ushort4 u0 = make_ushort4(f2bf(f0.x*0.125f), f2bf(f0.y*0.125f), f2bf(f0.z*0.125f), f2bf(f0.w*0.125f));
      ushort4 u1 = make_ushort4(f2bf(f1.x*0.125f), f2bf(f1.y*0.125f), f2bf(f1.z*0.125f), f2bf(f1.w*0.125f));
      int off = row * 128 + ((2 * (d0 + 8 * i)) ^ ((row & 7) << 4));
      *(ushort4*)(sQP + off)     = u0;
      *(ushort4*)(sQP + off + 8) = u1;
    }
  }
  __syncthreads();
  // hoist Q A-frags (row = w*16 + fr)
  bf16x8 qf[2];
  {
    int row = w * 16 + fr;
    qf[0] = *(const bf16x8*)(sQP + row * 128 + ((2 * (fq * 8))      ^ ((row & 7) << 4)));
    qf[1] = *(const bf16x8*)(sQP + row * 128 + ((2 * (32 + fq * 8)) ^ ((row & 7) << 4)));
  }
  __syncthreads();   // sQP now free for P

  float m_r[4] = {-1e30f, -1e30f, -1e30f, -1e30f};
  float l_r[4] = {0.f, 0.f, 0.f, 0.f};
  f32x4 acc_o[4];
  #pragma unroll
  for (int j = 0; j < 4; ++j) acc_o[j] = (f32x4){0.f, 0.f, 0.f, 0.f};

  for (int ib = 0; ib < nkb; ++ib) {
    const int kb = (nkb == 64) ? ib : klist[ib];
    const size_t kbase = ((size_t)b * 4096 + (size_t)kb * 64) * 768 + h * 64;
    // stage K [key][d] + V^T [d][key]
    {
      int key = t >> 2, d0 = (t & 3) * 16;
      const bf* kp = &K[kbase + (size_t)key * 768 + d0];
      #pragma unroll
      for (int i = 0; i < 2; ++i) {
        ushort4 u0 = *(const ushort4*)(kp + 8 * i);
        ushort4 u1 = *(const ushort4*)(kp + 8 * i + 4);
        int off = key * 128 + ((2 * (d0 + 8 * i)) ^ ((key & 7) << 4));
        *(ushort4*)(sK + off)     = u0;
        *(ushort4*)(sK + off + 8) = u1;
      }
      const bf* vp = &V[kbase + (size_t)key * 768 + d0];
      #pragma unroll
      for (int i = 0; i < 4; ++i) {
        ushort4 u = *(const ushort4*)(vp + 4 * i);
        unsigned short vals[4] = {u.x, u.y, u.z, u.w};
        #pragma unroll
        for (int e = 0; e < 4; ++e) {
          int d = d0 + 4 * i + e;
          *(unsigned short*)(sVT + d * 128 + ((2 * key) ^ ((d & 7) << 4))) = vals[e];
        }
      }
    }
    __syncthreads();
    // S = (Q/8) K^T  (8 MFMAs/wave)
    f32x4 s4[4];
    #pragma unroll
    for (int j = 0; j < 4; ++j) s4[j] = (f32x4){0.f, 0.f, 0.f, 0.f};
    #pragma unroll
    for (int kk = 0; kk < 2; ++kk) {
      #pragma unroll
      for (int j = 0; j < 4; ++j) {
        int key = j * 16 + fr;
        bf16x8 kf = *(const bf16x8*)(sK + key * 128 + ((2 * (kk * 32 + fq * 8)) ^ ((key & 7) << 4)));
        s4[j] = __builtin_amdgcn_mfma_f32_16x16x32_bf16(qf[kk], kf, s4[j], 0, 0, 0);
      }
    }
    // online softmax: lane owns rows fq*4+r; reduce over fr lanes (masks 1,2,4,8)
    float c_r[4];
    #pragma unroll
    for (int r = 0; r < 4; ++r) {
      float mx = fmaxf(fmaxf(s4[0][r], s4[1][r]), fmaxf(s4[2][r], s4[3][r]));
      #pragma unroll
      for (int m = 1; m < 16; m <<= 1) mx = fmaxf(mx, __shfl_xor(mx, m, 64));
      float mn = fmaxf(mx, m_r[r]);
      float c  = expf(m_r[r] - mn);
      float p0 = expf(s4[0][r] - mn), p1 = expf(s4[1][r] - mn);
      float p2 = expf(s4[2][r] - mn), p3 = expf(s4[3][r] - mn);
      s4[0][r] = p0; s4[1][r] = p1; s4[2][r] = p2; s4[3][r] = p3;
      float sum = p0 + p1 + p2 + p3;
      #pragma unroll
      for (int m = 1; m < 16; m <<= 1) sum += __shfl_xor(sum, m, 64);
      l_r[r] = l_r[r] * c + sum;
      m_r[r] = mn;
      c_r[r] = c;
    }
    // rescale O accumulator
    #pragma unroll
    for (int j = 0; j < 4; ++j)
      #pragma unroll
      for (int r = 0; r < 4; ++r) acc_o[j][r] *= c_r[r];
    // write P (bf16) into sQP: row = w*16+fq*4+r, col = j*16+fr
    {
      #pragma unroll
      for (int r = 0; r < 4; ++r) {
        int prow = w * 16 + fq * 4 + r;
        int rs = prow * 128, sw = (prow & 7) << 4;
        #pragma unroll
        for (int j = 0; j < 4; ++j)
          *(unsigned short*)(sQP + rs + ((2 * (j * 16 + fr)) ^ sw)) = f2bf(s4[j][r]);
      }
    }
    __syncthreads();
    // O += P V  (8 MFMAs/wave); A=P row=w*16+fr, B=V^T col=j*16+fr
    #pragma unroll
    for (int kk = 0; kk < 2; ++kk) {
      int prow = w * 16 + fr;
      bf16x8 pf = *(const bf16x8*)(sQP + prow * 128 + ((2 * (kk * 32 + fq * 8)) ^ ((prow & 7) << 4)));
      #pragma unroll
      for (int j = 0; j < 4; ++j) {
        int col = j * 16 + fr;
        bf16x8 vf = *(const bf16x8*)(sVT + col * 128 + ((2 * (kk * 32 + fq * 8)) ^ ((col & 7) << 4)));
        acc_o[j] = __builtin_amdgcn_mfma_f32_16x16x32_bf16(pf, vf, acc_o[j], 0, 0, 0);
      }
    }
    __syncthreads();
  }
  // epilogue: O / l -> ctx (in-place over Q region)
  {
    int row0 = w * 16 + fq * 4;
    #pragma unroll
    for (int r = 0; r < 4; ++r) {
      float inv = 1.f / l_r[r];
      size_t rowoff = qbase + (size_t)(row0 + r) * 768;
      #pragma unroll
      for (int j = 0; j < 4; ++j)
        ctx[rowoff + j * 16 + fr] = acc_o[j][r] * inv;
    }
  }
}

// ---------------- LayerNorm(a + res) * g + b ----------------
template <typename TR, typename TO>
__global__ __launch_bounds__(256) void ln_kernel(
    const float* __restrict__ a, const TR* __restrict__ res,
    const float* __restrict__ g, const float* __restrict__ bb,
    TO* __restrict__ out)
{
  const int row = blockIdx.x, t = threadIdx.x;
  __shared__ float buf[768];
  __shared__ float rs[4], rss[4];
  const size_t base = (size_t)row * 768;
  float s = 0.f, ss = 0.f;
  for (int c = t; c < 768; c += 256) {
    float rv;
    if constexpr (sizeof(TR) == 2) rv = bf2f(res[base + c]);
    else                           rv = res[base + c];
    float v = a[base + c] + rv;
    buf[c] = v;
    s += v;
    ss = fmaf(v, v, ss);
  }
  #pragma unroll
  for (int off = 32; off > 0; off >>= 1) {
    s  += __shfl_down(s, off, 64);
    ss += __shfl_down(ss, off, 64);
  }
  if ((t & 63) == 0) { rs[t >> 6] = s; rss[t >> 6] = ss; }
  __syncthreads();
  float S  = rs[0] + rs[1] + rs[2] + rs[3];
  float SS = rss[0] + rss[1] + rss[2] + rss[3];
  float mu  = S * (1.f / 768.f);
  float var = SS * (1.f / 768.f) - mu * mu;
  float inv = rsqrtf(var + 1e-5f);
  for (int c = t; c < 768; c += 256) {
    float v = (buf[c] - mu) * inv * g[c] + bb[c];
    if constexpr (sizeof(TO) == 2) out[base + c] = f2bf(v);
    else                           out[base + c] = v;
  }
}

extern "C" void kernel_launch(void* const* d_in, const int* in_sizes, int n_in,
                              void* d_out, int out_size, void* d_ws, size_t ws_size,
                              hipStream_t stream)
{
  const float* x   = (const float*)d_in[0];
  const int*   rnd = (const int*)d_in[1];
  const float* Wq  = (const float*)d_in[2];
  const float* bq  = (const float*)d_in[3];
  const float* Wk  = (const float*)d_in[4];
  const float* bk  = (const float*)d_in[5];
  const float* Wv  = (const float*)d_in[6];
  const float* bv  = (const float*)d_in[7];
  const float* g1  = (const float*)d_in[8];
  const float* be1 = (const float*)d_in[9];
  const float* W1  = (const float*)d_in[10];
  const float* b1  = (const float*)d_in[11];
  const float* W2  = (const float*)d_in[12];
  const float* b2  = (const float*)d_in[13];
  const float* g2  = (const float*)d_in[14];
  const float* be2 = (const float*)d_in[15];
  float* out = (float*)d_out;

  const size_t MT = 8192;  // B*S rows
  bf* Kb  = (bf*)d_ws;           // 8192*768 bf16
  bf* Vb  = Kb + MT * 768;       // 8192*768 bf16
  float* Qb  = out;              // Q f32 in d_out; attn runs in-place
  float* ctx = out;
  bf* h1  = Kb;                  // reuses K slot after attention
  bf* f1c = Vb;                  // reuses V slot after attention
  float* f2 = out;               // FFN accumulator in d_out

  dim3 blk(256);
  dim3 g768(768 / 64, MT / 128);
  mgemm_k<float, float><<<g768, blk, 0, stream>>>(x, Wq, bq, Qb, MT, 768, 768, 768, 0, 0);
  mgemm_k<float, bf   ><<<g768, blk, 0, stream>>>(x, Wk, bk, Kb, MT, 768, 768, 768, 0, 0);
  mgemm_k<float, bf   ><<<g768, blk, 0, stream>>>(x, Wv, bv, Vb, MT, 768, 768, 768, 0, 0);
  attn3_kernel<<<dim3(1536), blk, 0, stream>>>(Qb, Kb, Vb, rnd, ctx);
  ln_kernel<float, bf><<<dim3(MT), blk, 0, stream>>>(ctx, x, g1, be1, h1);
  for (int c = 0; c < 4; ++c) {
    mgemm_k<bf, bf   ><<<g768, blk, 0, stream>>>(h1, W1 + c * 768, b1 + c * 768, f1c,
                                                 MT, 768, 768, 3072, 1, 0);
    mgemm_k<bf, float><<<g768, blk, 0, stream>>>(f1c, W2 + (size_t)c * 768 * 768,
                                                 (c == 0 ? b2 : (const float*)nullptr), f2,
                                                 MT, 768, 768, 768, 0, (c == 0 ? 0 : 1));
  }
  ln_kernel<bf, float><<<dim3(MT), blk, 0, stream>>>(f2, h1, g2, be2, out);
}

// Round 11
// 517.668 us; speedup vs baseline: 8.4599x; 1.4024x over previous
//
#include <hip/hip_runtime.h>
#include <cmath>

// B=2, S=4096, DM=768, H=12, FF=3072, BLOCK=64, NB=64, R=3, d=64
// Round 11: attn4 = double-buffered K/VT (register prefetch), conflict-free VT
// staging, 1 barrier/iter (wave-local P), heavy WGs first, setprio around MFMA.
// GEMM/LN unchanged from round 9/10.

typedef unsigned short bf;
typedef __attribute__((ext_vector_type(8))) short bf16x8;
typedef __attribute__((ext_vector_type(4))) float f32x4;

__device__ __forceinline__ float bf2f(bf u) { return __uint_as_float(((unsigned)u) << 16); }
__device__ __forceinline__ bf f2bf(float f) {
  unsigned x = __float_as_uint(f);
  x += 0x7FFFu + ((x >> 16) & 1u);   // round-to-nearest-even
  return (bf)(x >> 16);
}
__device__ __forceinline__ float4 ld4f(const float* p) { return *(const float4*)p; }
__device__ __forceinline__ float4 ld4f(const bf* p) {
  ushort4 u = *(const ushort4*)(p);
  return make_float4(bf2f(u.x), bf2f(u.y), bf2f(u.z), bf2f(u.w));
}

// ---- MFMA GEMM (verified round 9): C = [beta*C] + A*B [+bias] [GELU] ----
template <typename TA, typename TC>
__global__ __launch_bounds__(256) void mgemm_k(
    const TA* __restrict__ A, const float* __restrict__ B,
    const float* __restrict__ bias, TC* __restrict__ C,
    int M, int N, int K, int ldb, int ep, int beta)
{
  __shared__ char smem[24576];
  char* sA = smem;
  char* sB = smem + 16384;
  const int t = threadIdx.x;
  const int bm = blockIdx.y * 128, bn = blockIdx.x * 64;
  const int lane = t & 63, wid = t >> 6;
  const int wm = wid >> 1, wn = wid & 1;
  const int fr = lane & 15, fq = lane >> 4;

  f32x4 acc[4][2];
  #pragma unroll
  for (int i = 0; i < 4; ++i)
    #pragma unroll
    for (int j = 0; j < 2; ++j) acc[i][j] = (f32x4){0.f, 0.f, 0.f, 0.f};

  const int bcol = t & 63, bkq = t >> 6;

  for (int k0 = 0; k0 < K; k0 += 64) {
    #pragma unroll
    for (int c = 0; c < 4; ++c) {
      int id = t + 256 * c;
      int row = id >> 3, kc = (id & 7) * 8;
      ushort4 lo, hi;
      if constexpr (sizeof(TA) == 4) {
        const float* ap = &A[(size_t)(bm + row) * K + k0 + kc];
        float4 f0 = *(const float4*)ap;
        float4 f1 = *(const float4*)(ap + 4);
        lo = make_ushort4(f2bf(f0.x), f2bf(f0.y), f2bf(f0.z), f2bf(f0.w));
        hi = make_ushort4(f2bf(f1.x), f2bf(f1.y), f2bf(f1.z), f2bf(f1.w));
      } else {
        const bf* ap = &A[(size_t)(bm + row) * K + k0 + kc];
        lo = *(const ushort4*)ap;
        hi = *(const ushort4*)(ap + 4);
      }
      int off = row * 128 + ((kc * 2) ^ ((row & 7) << 4));
      *(ushort4*)(sA + off)     = lo;
      *(ushort4*)(sA + off + 8) = hi;
    }
    #pragma unroll
    for (int q = 0; q < 4; ++q) {
      int k = bkq * 16 + q * 4;
      const float* bp = &B[(size_t)(k0 + k) * ldb + bn + bcol];
      float b0 = bp[0];
      float b1 = bp[ldb];
      float b2 = bp[2 * (size_t)ldb];
      float b3 = bp[3 * (size_t)ldb];
      ushort4 pk = make_ushort4(f2bf(b0), f2bf(b1), f2bf(b2), f2bf(b3));
      int off = bcol * 128 + ((k * 2) ^ ((bcol & 7) << 4));
      *(ushort4*)(sB + off) = pk;
    }
    __syncthreads();
    #pragma unroll
    for (int kk = 0; kk < 2; ++kk) {
      const int kb = (kk * 32 + fq * 8) * 2;
      bf16x8 a[4], b[2];
      #pragma unroll
      for (int i = 0; i < 4; ++i) {
        int row = wm * 64 + i * 16 + fr;
        a[i] = *(const bf16x8*)(sA + row * 128 + (kb ^ ((row & 7) << 4)));
      }
      #pragma unroll
      for (int j = 0; j < 2; ++j) {
        int col = wn * 32 + j * 16 + fr;
        b[j] = *(const bf16x8*)(sB + col * 128 + (kb ^ ((col & 7) << 4)));
      }
      #pragma unroll
      for (int i = 0; i < 4; ++i)
        #pragma unroll
        for (int j = 0; j < 2; ++j)
          acc[i][j] = __builtin_amdgcn_mfma_f32_16x16x32_bf16(a[i], b[j], acc[i][j], 0, 0, 0);
    }
    __syncthreads();
  }
  #pragma unroll
  for (int j = 0; j < 2; ++j) {
    int col = bn + wn * 32 + j * 16 + fr;
    float bias_v = bias ? bias[col] : 0.f;
    #pragma unroll
    for (int i = 0; i < 4; ++i) {
      int row0 = bm + wm * 64 + i * 16 + fq * 4;
      #pragma unroll
      for (int r = 0; r < 4; ++r) {
        size_t idx = (size_t)(row0 + r) * N + col;
        float v = acc[i][j][r] + bias_v;
        if (ep == 1) v = 0.5f * v * (1.0f + erff(v * 0.70710678118654752f));
        if (beta) {
          if constexpr (sizeof(TC) == 2) v += bf2f(C[idx]);
          else                           v += C[idx];
        }
        if constexpr (sizeof(TC) == 2) C[idx] = f2bf(v);
        else                           C[idx] = v;
      }
    }
  }
}

// stage one prefetched K/V block into LDS buffers (layouts as read by MFMA frags)
__device__ __forceinline__ void stage_kv(char* bK, char* bVT,
    int kkey, int kd0, int vkey, int w,
    uint4 k0, uint4 k1, uint4 v0, uint4 v1)
{
  const int sw = (kkey & 7) << 4;
  *(uint4*)(bK + kkey * 128 + ((2 * kd0) ^ sw))      = k0;
  *(uint4*)(bK + kkey * 128 + ((2 * kd0 + 16) ^ sw)) = k1;
  union { uint4 q; unsigned short s[8]; } a, c;
  a.q = v0; c.q = v1;
  #pragma unroll
  for (int i = 0; i < 8; ++i) {
    int d = w * 16 + i;
    *(unsigned short*)(bVT + d * 128 + ((2 * vkey) ^ ((d & 7) << 4))) = a.s[i];
  }
  #pragma unroll
  for (int i = 0; i < 8; ++i) {
    int d = w * 16 + 8 + i;
    *(unsigned short*)(bVT + d * 128 + ((2 * vkey) ^ ((d & 7) << 4))) = c.s[i];
  }
}

// ---------------- BigBird attention v4: MFMA + dbuf prefetch ----------------
// wg<48: heavy (n=0/63, 64 key blocks). Else light (7-8 blocks).
__global__ __launch_bounds__(256) void attn4_kernel(
    const float* __restrict__ Q, const bf* __restrict__ K,
    const bf* __restrict__ V, const int* __restrict__ rnd,
    float* __restrict__ ctx)
{
  __shared__ char sQP[8192];
  __shared__ char sKV[2][16384];   // per buf: K [0,8192), VT [8192,16384)
  __shared__ int klist[8];
  const int t = threadIdx.x;
  const int lane = t & 63, w = t >> 6;
  const int fr = lane & 15, fq = lane >> 4;
  const int wg = blockIdx.x;
  int b, h, n, nkb;
  if (wg < 48) {
    n = (wg & 1) ? 63 : 0;
    int bh = wg >> 1; h = bh % 12; b = bh / 12;
    nkb = 64;
  } else {
    int idx = wg - 48;
    n = 1 + (idx % 62);
    int bh = idx / 62; h = bh % 12; b = bh / 12;
    nkb = (n == 1 || n == 62) ? 7 : 8;
    if (t == 0) {
      int cnt = 0;
      if (n == 1)       { klist[0]=0; klist[1]=1;  klist[2]=2;  klist[3]=63; cnt=4; }
      else if (n == 62) { klist[0]=0; klist[1]=61; klist[2]=62; klist[3]=63; cnt=4; }
      else              { klist[0]=0; klist[1]=n-1; klist[2]=n; klist[3]=n+1; cnt=4; }
      for (int j = 0; j < 3; ++j) klist[cnt++] = rnd[(h * 62 + (n - 1)) * 3 + j];
      if (n != 1 && n != 62) klist[cnt++] = 63;
    }
  }
  const size_t qbase = ((size_t)b * 4096 + (size_t)n * 64) * 768 + h * 64;

  // stage Q -> bf16 pre-scaled by 1/8
  {
    int row = t >> 2, d0 = (t & 3) * 16;
    const float* qp = &Q[qbase + (size_t)row * 768 + d0];
    #pragma unroll
    for (int i = 0; i < 2; ++i) {
      float4 f0 = *(const float4*)(qp + 8 * i);
      float4 f1 = *(const float4*)(qp + 8 * i + 4);
      ushort4 u0 = make_ushort4(f2bf(f0.x*0.125f), f2bf(f0.y*0.125f), f2bf(f0.z*0.125f), f2bf(f0.w*0.125f));
      ushort4 u1 = make_ushort4(f2bf(f1.x*0.125f), f2bf(f1.y*0.125f), f2bf(f1.z*0.125f), f2bf(f1.w*0.125f));
      int off = row * 128 + ((2 * (d0 + 8 * i)) ^ ((row & 7) << 4));
      *(ushort4*)(sQP + off)     = u0;
      *(ushort4*)(sQP + off + 8) = u1;
    }
  }
  __syncthreads();   // Q + klist visible
  bf16x8 qf[2];
  {
    int row = w * 16 + fr;
    qf[0] = *(const bf16x8*)(sQP + row * 128 + ((2 * (fq * 8))      ^ ((row & 7) << 4)));
    qf[1] = *(const bf16x8*)(sQP + row * 128 + ((2 * (32 + fq * 8)) ^ ((row & 7) << 4)));
  }

  const int kkey = t >> 2, kd0 = (t & 3) * 16;   // K staging: 32B @ [kkey][kd0..+16]
  const int vkey = lane;                          // VT staging: V[vkey][w*16..+16]

  // prefetch + stage block 0 into buf0
  uint4 pk0, pk1, pv0, pv1;
  {
    int kb = (nkb == 64) ? 0 : klist[0];
    size_t kbase = ((size_t)b * 4096 + (size_t)kb * 64) * 768 + h * 64;
    const bf* kp = &K[kbase + (size_t)kkey * 768 + kd0];
    pk0 = *(const uint4*)kp;  pk1 = *(const uint4*)(kp + 8);
    const bf* vp = &V[kbase + (size_t)vkey * 768 + w * 16];
    pv0 = *(const uint4*)vp;  pv1 = *(const uint4*)(vp + 8);
  }
  stage_kv(sKV[0], sKV[0] + 8192, kkey, kd0, vkey, w, pk0, pk1, pv0, pv1);

  float m_r[4] = {-1e30f, -1e30f, -1e30f, -1e30f};
  float l_r[4] = {0.f, 0.f, 0.f, 0.f};
  f32x4 acc_o[4];
  #pragma unroll
  for (int j = 0; j < 4; ++j) acc_o[j] = (f32x4){0.f, 0.f, 0.f, 0.f};

  for (int ib = 0; ib < nkb; ++ib) {
    char* bK  = sKV[ib & 1];
    char* bVT = bK + 8192;
    const bool pf = (ib + 1 < nkb);
    if (pf) {   // issue next block's loads (latency hides under this iter)
      int kb = (nkb == 64) ? (ib + 1) : klist[ib + 1];
      size_t kbase = ((size_t)b * 4096 + (size_t)kb * 64) * 768 + h * 64;
      const bf* kp = &K[kbase + (size_t)kkey * 768 + kd0];
      pk0 = *(const uint4*)kp;  pk1 = *(const uint4*)(kp + 8);
      const bf* vp = &V[kbase + (size_t)vkey * 768 + w * 16];
      pv0 = *(const uint4*)vp;  pv1 = *(const uint4*)(vp + 8);
    }
    __syncthreads();   // buf[ib&1] ready; all waves past reads of buf[(ib&1)^1]
    // S = (Q/8) K^T
    f32x4 s4[4];
    #pragma unroll
    for (int j = 0; j < 4; ++j) s4[j] = (f32x4){0.f, 0.f, 0.f, 0.f};
    __builtin_amdgcn_s_setprio(1);
    #pragma unroll
    for (int kk = 0; kk < 2; ++kk) {
      #pragma unroll
      for (int j = 0; j < 4; ++j) {
        int key = j * 16 + fr;
        bf16x8 kf = *(const bf16x8*)(bK + key * 128 + ((2 * (kk * 32 + fq * 8)) ^ ((key & 7) << 4)));
        s4[j] = __builtin_amdgcn_mfma_f32_16x16x32_bf16(qf[kk], kf, s4[j], 0, 0, 0);
      }
    }
    __builtin_amdgcn_s_setprio(0);
    // online softmax (lane owns rows fq*4+r; reduce across fr lanes)
    float c_r[4];
    #pragma unroll
    for (int r = 0; r < 4; ++r) {
      float mx = fmaxf(fmaxf(s4[0][r], s4[1][r]), fmaxf(s4[2][r], s4[3][r]));
      #pragma unroll
      for (int m = 1; m < 16; m <<= 1) mx = fmaxf(mx, __shfl_xor(mx, m, 64));
      float mn = fmaxf(mx, m_r[r]);
      float c  = __expf(m_r[r] - mn);
      float p0 = __expf(s4[0][r] - mn), p1 = __expf(s4[1][r] - mn);
      float p2 = __expf(s4[2][r] - mn), p3 = __expf(s4[3][r] - mn);
      s4[0][r] = p0; s4[1][r] = p1; s4[2][r] = p2; s4[3][r] = p3;
      float sum = p0 + p1 + p2 + p3;
      #pragma unroll
      for (int m = 1; m < 16; m <<= 1) sum += __shfl_xor(sum, m, 64);
      l_r[r] = l_r[r] * c + sum;
      m_r[r] = mn;
      c_r[r] = c;
    }
    #pragma unroll
    for (int j = 0; j < 4; ++j)
      #pragma unroll
      for (int r = 0; r < 4; ++r) acc_o[j][r] *= c_r[r];
    // P -> sQP (wave-local rows w*16..+15; no barrier needed before own-wave read)
    #pragma unroll
    for (int r = 0; r < 4; ++r) {
      int prow = w * 16 + fq * 4 + r;
      int rs = prow * 128, sw = (prow & 7) << 4;
      #pragma unroll
      for (int j = 0; j < 4; ++j)
        *(unsigned short*)(sQP + rs + ((2 * (j * 16 + fr)) ^ sw)) = f2bf(s4[j][r]);
    }
    // stage next block into the other buffer (safe: others done reading it)
    if (pf)
      stage_kv(sKV[(ib & 1) ^ 1], sKV[(ib & 1) ^ 1] + 8192, kkey, kd0, vkey, w,
               pk0, pk1, pv0, pv1);
    // O += P V
    __builtin_amdgcn_s_setprio(1);
    #pragma unroll
    for (int kk = 0; kk < 2; ++kk) {
      int prow = w * 16 + fr;
      bf16x8 pf8 = *(const bf16x8*)(sQP + prow * 128 + ((2 * (kk * 32 + fq * 8)) ^ ((prow & 7) << 4)));
      #pragma unroll
      for (int j = 0; j < 4; ++j) {
        int col = j * 16 + fr;
        bf16x8 vf = *(const bf16x8*)(bVT + col * 128 + ((2 * (kk * 32 + fq * 8)) ^ ((col & 7) << 4)));
        acc_o[j] = __builtin_amdgcn_mfma_f32_16x16x32_bf16(pf8, vf, acc_o[j], 0, 0, 0);
      }
    }
    __builtin_amdgcn_s_setprio(0);
  }
  // epilogue: O / l -> ctx (in-place over Q region)
  {
    int row0 = w * 16 + fq * 4;
    #pragma unroll
    for (int r = 0; r < 4; ++r) {
      float inv = 1.f / l_r[r];
      size_t rowoff = qbase + (size_t)(row0 + r) * 768;
      #pragma unroll
      for (int j = 0; j < 4; ++j)
        ctx[rowoff + j * 16 + fr] = acc_o[j][r] * inv;
    }
  }
}

// ---------------- LayerNorm(a + res) * g + b ----------------
template <typename TR, typename TO>
__global__ __launch_bounds__(256) void ln_kernel(
    const float* __restrict__ a, const TR* __restrict__ res,
    const float* __restrict__ g, const float* __restrict__ bb,
    TO* __restrict__ out)
{
  const int row = blockIdx.x, t = threadIdx.x;
  __shared__ float buf[768];
  __shared__ float rs[4], rss[4];
  const size_t base = (size_t)row * 768;
  float s = 0.f, ss = 0.f;
  for (int c = t; c < 768; c += 256) {
    float rv;
    if constexpr (sizeof(TR) == 2) rv = bf2f(res[base + c]);
    else                           rv = res[base + c];
    float v = a[base + c] + rv;
    buf[c] = v;
    s += v;
    ss = fmaf(v, v, ss);
  }
  #pragma unroll
  for (int off = 32; off > 0; off >>= 1) {
    s  += __shfl_down(s, off, 64);
    ss += __shfl_down(ss, off, 64);
  }
  if ((t & 63) == 0) { rs[t >> 6] = s; rss[t >> 6] = ss; }
  __syncthreads();
  float S  = rs[0] + rs[1] + rs[2] + rs[3];
  float SS = rss[0] + rss[1] + rss[2] + rss[3];
  float mu  = S * (1.f / 768.f);
  float var = SS * (1.f / 768.f) - mu * mu;
  float inv = rsqrtf(var + 1e-5f);
  for (int c = t; c < 768; c += 256) {
    float v = (buf[c] - mu) * inv * g[c] + bb[c];
    if constexpr (sizeof(TO) == 2) out[base + c] = f2bf(v);
    else                           out[base + c] = v;
  }
}

extern "C" void kernel_launch(void* const* d_in, const int* in_sizes, int n_in,
                              void* d_out, int out_size, void* d_ws, size_t ws_size,
                              hipStream_t stream)
{
  const float* x   = (const float*)d_in[0];
  const int*   rnd = (const int*)d_in[1];
  const float* Wq  = (const float*)d_in[2];
  const float* bq  = (const float*)d_in[3];
  const float* Wk  = (const float*)d_in[4];
  const float* bk  = (const float*)d_in[5];
  const float* Wv  = (const float*)d_in[6];
  const float* bv  = (const float*)d_in[7];
  const float* g1  = (const float*)d_in[8];
  const float* be1 = (const float*)d_in[9];
  const float* W1  = (const float*)d_in[10];
  const float* b1  = (const float*)d_in[11];
  const float* W2  = (const float*)d_in[12];
  const float* b2  = (const float*)d_in[13];
  const float* g2  = (const float*)d_in[14];
  const float* be2 = (const float*)d_in[15];
  float* out = (float*)d_out;

  const size_t MT = 8192;  // B*S rows
  bf* Kb  = (bf*)d_ws;           // 8192*768 bf16
  bf* Vb  = Kb + MT * 768;       // 8192*768 bf16
  float* Qb  = out;              // Q f32 in d_out; attn runs in-place
  float* ctx = out;
  bf* h1  = Kb;                  // reuses K slot after attention
  bf* f1c = Vb;                  // reuses V slot after attention
  float* f2 = out;               // FFN accumulator in d_out

  dim3 blk(256);
  dim3 g768(768 / 64, MT / 128);
  mgemm_k<float, float><<<g768, blk, 0, stream>>>(x, Wq, bq, Qb, MT, 768, 768, 768, 0, 0);
  mgemm_k<float, bf   ><<<g768, blk, 0, stream>>>(x, Wk, bk, Kb, MT, 768, 768, 768, 0, 0);
  mgemm_k<float, bf   ><<<g768, blk, 0, stream>>>(x, Wv, bv, Vb, MT, 768, 768, 768, 0, 0);
  attn4_kernel<<<dim3(48 + 2 * 12 * 62), blk, 0, stream>>>(Qb, Kb, Vb, rnd, ctx);
  ln_kernel<float, bf><<<dim3(MT), blk, 0, stream>>>(ctx, x, g1, be1, h1);
  for (int c = 0; c < 4; ++c) {
    mgemm_k<bf, bf   ><<<g768, blk, 0, stream>>>(h1, W1 + c * 768, b1 + c * 768, f1c,
                                                 MT, 768, 768, 3072, 1, 0);
    mgemm_k<bf, float><<<g768, blk, 0, stream>>>(f1c, W2 + (size_t)c * 768 * 768,
                                                 (c == 0 ? b2 : (const float*)nullptr), f2,
                                                 MT, 768, 768, 768, 0, (c == 0 ? 0 : 1));
  }
  ln_kernel<bf, float><<<dim3(MT), blk, 0, stream>>>(f2, h1, g2, be2, out);
}